// Round 1
// baseline (614.478 us; speedup 1.0000x reference)
//
#include <hip/hip_runtime.h>

#define N_NODES 50000
#define N_EDGES 800000
#define E_TOT   850000            // N_EDGES + N_NODES self loops
#define IN_CH   128
#define HID     64
#define HEADS   4
#define C1      256               // HEADS*HID
#define OUT_CH  64
#define NEG_SLOPE 0.2f
#define EPSV    1e-16f

// ---------------- CSR build (group edges by dst) ----------------
__global__ void k_count(const int* __restrict__ ei, int* __restrict__ deg) {
    int e = blockIdx.x * blockDim.x + threadIdx.x;
    if (e >= E_TOT) return;
    int d = (e < N_EDGES) ? ei[N_EDGES + e] : (e - N_EDGES);
    atomicAdd(&deg[d], 1);
}

__global__ __launch_bounds__(1024) void k_scan(const int* __restrict__ deg,
                                               int* __restrict__ rowptr,
                                               int* __restrict__ cursor) {
    __shared__ int wsum[16];
    __shared__ int carry_s;
    const int tid = threadIdx.x;
    const int lane = tid & 63;
    const int wv = tid >> 6;
    if (tid == 0) carry_s = 0;
    __syncthreads();
    for (int base = 0; base < N_NODES; base += 1024) {
        int i = base + tid;
        int v = (i < N_NODES) ? deg[i] : 0;
        int s = v;
        #pragma unroll
        for (int d = 1; d < 64; d <<= 1) {
            int t = __shfl_up(s, d, 64);
            if (lane >= d) s += t;
        }
        if (lane == 63) wsum[wv] = s;
        __syncthreads();
        if (wv == 0 && lane < 16) {
            int w = wsum[lane];
            #pragma unroll
            for (int d = 1; d < 16; d <<= 1) {
                int t = __shfl_up(w, d, 64);
                if (lane >= d) w += t;
            }
            wsum[lane] = w;
        }
        __syncthreads();
        int excl = carry_s + ((wv > 0) ? wsum[wv - 1] : 0) + (s - v);
        if (i < N_NODES) { rowptr[i] = excl; cursor[i] = excl; }
        __syncthreads();
        if (tid == 0) carry_s += wsum[15];
        __syncthreads();
    }
    if (tid == 0) rowptr[N_NODES] = carry_s;
}

__global__ void k_scatter(const int* __restrict__ ei, int* __restrict__ cursor,
                          int* __restrict__ csr_src) {
    int e = blockIdx.x * blockDim.x + threadIdx.x;
    if (e >= E_TOT) return;
    int s, d;
    if (e < N_EDGES) { s = ei[e]; d = ei[N_EDGES + e]; }
    else             { s = d = e - N_EDGES; }
    int pos = atomicAdd(&cursor[d], 1);
    csr_src[pos] = s;
}

// ---------------- GEMM1: h1 = x @ W1, fused attention logits ----------------
#define TM1 32
__global__ __launch_bounds__(256) void k_gemm1(
    const float* __restrict__ x, const float* __restrict__ W1,
    const float* __restrict__ a_s1, const float* __restrict__ a_d1,
    float* __restrict__ h1, float* __restrict__ l1s, float* __restrict__ l1d) {
    __shared__ float xs[TM1 * IN_CH];            // 16 KB
    const int base = blockIdx.x * TM1;
    const int rows = min(TM1, N_NODES - base);
    const int tid = threadIdx.x;
    for (int i = tid; i < TM1 * IN_CH / 4; i += 256) {
        int flat = i * 4;
        int m = flat >> 7;                       // /128
        float4 v = make_float4(0.f, 0.f, 0.f, 0.f);
        if (m < rows) v = *(const float4*)(x + (size_t)(base + m) * IN_CH + (flat & 127));
        *(float4*)(xs + flat) = v;
    }
    __syncthreads();
    const int c = tid;                           // output col 0..255
    float acc[TM1];
    #pragma unroll
    for (int m = 0; m < TM1; ++m) acc[m] = 0.f;
    for (int k = 0; k < IN_CH; k += 4) {
        float w0 = W1[(k + 0) * C1 + c];
        float w1 = W1[(k + 1) * C1 + c];
        float w2 = W1[(k + 2) * C1 + c];
        float w3 = W1[(k + 3) * C1 + c];
        #pragma unroll
        for (int m = 0; m < TM1; ++m) {
            const float4 xv = *(const float4*)(xs + m * IN_CH + k);
            acc[m] = fmaf(xv.x, w0, acc[m]);
            acc[m] = fmaf(xv.y, w1, acc[m]);
            acc[m] = fmaf(xv.z, w2, acc[m]);
            acc[m] = fmaf(xv.w, w3, acc[m]);
        }
    }
    const float avs = a_s1[c];
    const float avd = a_d1[c];
    const int lane = tid & 63;
    const int hh = tid >> 6;                     // head == wave
    for (int m = 0; m < rows; ++m) {
        float v = acc[m];
        h1[(size_t)(base + m) * C1 + c] = v;
        float ps = v * avs, pd = v * avd;
        #pragma unroll
        for (int d = 1; d < 64; d <<= 1) {
            ps += __shfl_xor(ps, d, 64);
            pd += __shfl_xor(pd, d, 64);
        }
        if (lane == 0) {
            l1s[(base + m) * HEADS + hh] = ps;
            l1d[(base + m) * HEADS + hh] = pd;
        }
    }
}

// ---------------- agg1: segment softmax + gather, relu(+b1) ----------------
__global__ __launch_bounds__(256) void k_agg1(
    const float* __restrict__ h1, const float* __restrict__ l1s, const float* __restrict__ l1d,
    const int* __restrict__ rowptr, const int* __restrict__ csr_src,
    const float* __restrict__ b1, float* __restrict__ out1) {
    const int n = blockIdx.x;
    const int tid = threadIdx.x;
    const int lane = tid & 63;
    const int hh = tid >> 6;                     // head == wave
    const int beg = rowptr[n], end = rowptr[n + 1];
    const float4 ldv = *(const float4*)(l1d + n * 4);
    // pass A: per-head max over all incoming edges
    float mx0 = -1e30f, mx1 = -1e30f, mx2 = -1e30f, mx3 = -1e30f;
    for (int e = beg + tid; e < end; e += 256) {
        int s = csr_src[e];
        const float4 ls = *(const float4*)(l1s + s * 4);
        float e0 = ls.x + ldv.x; e0 = (e0 > 0.f) ? e0 : NEG_SLOPE * e0;
        float e1 = ls.y + ldv.y; e1 = (e1 > 0.f) ? e1 : NEG_SLOPE * e1;
        float e2 = ls.z + ldv.z; e2 = (e2 > 0.f) ? e2 : NEG_SLOPE * e2;
        float e3 = ls.w + ldv.w; e3 = (e3 > 0.f) ? e3 : NEG_SLOPE * e3;
        mx0 = fmaxf(mx0, e0); mx1 = fmaxf(mx1, e1);
        mx2 = fmaxf(mx2, e2); mx3 = fmaxf(mx3, e3);
    }
    #pragma unroll
    for (int d = 1; d < 64; d <<= 1) {
        mx0 = fmaxf(mx0, __shfl_xor(mx0, d, 64));
        mx1 = fmaxf(mx1, __shfl_xor(mx1, d, 64));
        mx2 = fmaxf(mx2, __shfl_xor(mx2, d, 64));
        mx3 = fmaxf(mx3, __shfl_xor(mx3, d, 64));
    }
    __shared__ float smx[4][4];                  // [wave][head]
    if (lane == 0) { smx[hh][0] = mx0; smx[hh][1] = mx1; smx[hh][2] = mx2; smx[hh][3] = mx3; }
    __syncthreads();
    const float mxh = fmaxf(fmaxf(smx[0][hh], smx[1][hh]), fmaxf(smx[2][hh], smx[3][hh]));
    const float ldh = (hh == 0) ? ldv.x : (hh == 1) ? ldv.y : (hh == 2) ? ldv.z : ldv.w;
    // pass B: unnormalized accumulate, divide at end
    float acc = 0.f, denom = 0.f;
    for (int e = beg; e < end; ++e) {
        int s = csr_src[e];
        float lg = l1s[s * HEADS + hh] + ldh;
        lg = (lg > 0.f) ? lg : NEG_SLOPE * lg;
        float w = __expf(lg - mxh);
        denom += w;
        acc = fmaf(w, h1[(size_t)s * C1 + tid], acc);
    }
    float r = acc / (denom + EPSV) + b1[tid];
    out1[(size_t)n * C1 + tid] = fmaxf(r, 0.f);  // relu between layers
}

// ---------------- GEMM2: h2 = out1 @ W2, fused logits (1 head) ----------------
#define TM2 32
__global__ __launch_bounds__(256) void k_gemm2(
    const float* __restrict__ xin, const float* __restrict__ W2,
    const float* __restrict__ a_s2, const float* __restrict__ a_d2,
    float* __restrict__ h2, float* __restrict__ l2s, float* __restrict__ l2d) {
    __shared__ float xs[TM2 * C1];               // 32 KB
    const int base = blockIdx.x * TM2;
    const int rows = min(TM2, N_NODES - base);
    const int tid = threadIdx.x;
    for (int i = tid; i < TM2 * C1 / 4; i += 256) {
        int flat = i * 4;
        int m = flat >> 8;                       // /256
        float4 v = make_float4(0.f, 0.f, 0.f, 0.f);
        if (m < rows) v = *(const float4*)(xin + (size_t)(base + m) * C1 + (flat & 255));
        *(float4*)(xs + flat) = v;
    }
    __syncthreads();
    const int c = tid & 63;
    const int g = tid >> 6;                      // wave g owns rows g, g+4, ..., g+28
    float acc[8];
    #pragma unroll
    for (int j = 0; j < 8; ++j) acc[j] = 0.f;
    for (int k = 0; k < C1; k += 4) {
        float w0 = W2[(k + 0) * HID + c];
        float w1 = W2[(k + 1) * HID + c];
        float w2 = W2[(k + 2) * HID + c];
        float w3 = W2[(k + 3) * HID + c];
        #pragma unroll
        for (int j = 0; j < 8; ++j) {
            const float4 xv = *(const float4*)(xs + (g + 4 * j) * C1 + k);
            acc[j] = fmaf(xv.x, w0, acc[j]);
            acc[j] = fmaf(xv.y, w1, acc[j]);
            acc[j] = fmaf(xv.z, w2, acc[j]);
            acc[j] = fmaf(xv.w, w3, acc[j]);
        }
    }
    const float avs = a_s2[c];
    const float avd = a_d2[c];
    #pragma unroll
    for (int j = 0; j < 8; ++j) {
        int m = g + 4 * j;
        if (m < rows) {                          // wave-uniform
            float v = acc[j];
            h2[(size_t)(base + m) * HID + c] = v;
            float ps = v * avs, pd = v * avd;
            #pragma unroll
            for (int d = 1; d < 64; d <<= 1) {
                ps += __shfl_xor(ps, d, 64);
                pd += __shfl_xor(pd, d, 64);
            }
            if (c == 0) { l2s[base + m] = ps; l2d[base + m] = pd; }
        }
    }
}

// ---------------- agg2 + final linear (wave per node) ----------------
__global__ __launch_bounds__(256) void k_agg2(
    const float* __restrict__ h2, const float* __restrict__ l2s, const float* __restrict__ l2d,
    const int* __restrict__ rowptr, const int* __restrict__ csr_src,
    const float* __restrict__ b2, const float* __restrict__ Wl, const float* __restrict__ bl,
    float* __restrict__ out) {
    __shared__ float Wls[HID * OUT_CH];          // 16 KB
    __shared__ float vsh[4][HID];
    const int tid = threadIdx.x;
    const int lane = tid & 63;
    const int wv = tid >> 6;
    for (int i = tid; i < HID * OUT_CH; i += 256) Wls[i] = Wl[i];
    const int n = blockIdx.x * 4 + wv;
    const bool active = (n < N_NODES);
    if (active) {
        const int beg = rowptr[n], end = rowptr[n + 1];
        const float ld = l2d[n];
        float mx = -1e30f;
        for (int e = beg + lane; e < end; e += 64) {
            float lg = l2s[csr_src[e]] + ld;
            lg = (lg > 0.f) ? lg : NEG_SLOPE * lg;
            mx = fmaxf(mx, lg);
        }
        #pragma unroll
        for (int d = 1; d < 64; d <<= 1) mx = fmaxf(mx, __shfl_xor(mx, d, 64));
        float acc = 0.f, denom = 0.f;
        for (int e = beg; e < end; ++e) {
            int s = csr_src[e];
            float lg = l2s[s] + ld;
            lg = (lg > 0.f) ? lg : NEG_SLOPE * lg;
            float w = __expf(lg - mx);
            denom += w;
            acc = fmaf(w, h2[(size_t)s * HID + lane], acc);
        }
        vsh[wv][lane] = acc / (denom + EPSV) + b2[lane];   // no relu after conv2
    }
    __syncthreads();
    if (active) {
        float o = bl[lane];
        #pragma unroll
        for (int c2 = 0; c2 < HID; ++c2)
            o = fmaf(vsh[wv][c2], Wls[c2 * OUT_CH + lane], o);
        out[(size_t)n * OUT_CH + lane] = o;
    }
}

extern "C" void kernel_launch(void* const* d_in, const int* in_sizes, int n_in,
                              void* d_out, int out_size, void* d_ws, size_t ws_size,
                              hipStream_t stream) {
    const float* x   = (const float*)d_in[0];
    const int*   ei  = (const int*)d_in[1];
    const float* W1  = (const float*)d_in[2];
    const float* as1 = (const float*)d_in[3];
    const float* ad1 = (const float*)d_in[4];
    const float* b1  = (const float*)d_in[5];
    const float* W2  = (const float*)d_in[6];
    const float* as2 = (const float*)d_in[7];
    const float* ad2 = (const float*)d_in[8];
    const float* b2  = (const float*)d_in[9];
    const float* Wl  = (const float*)d_in[10];
    const float* bl  = (const float*)d_in[11];
    float* out = (float*)d_out;

    char* p = (char*)d_ws;
    auto alloc = [&](size_t bytes) {
        char* r = p;
        p += (bytes + 255) & ~(size_t)255;
        return r;
    };
    int* deg      = (int*)alloc((size_t)N_NODES * 4);
    int* rowptr   = (int*)alloc((size_t)(N_NODES + 1) * 4);
    int* cursor   = (int*)alloc((size_t)N_NODES * 4);
    int* csr_src  = (int*)alloc((size_t)E_TOT * 4);
    float* h1     = (float*)alloc((size_t)N_NODES * C1 * 4);
    float* l1s    = (float*)alloc((size_t)N_NODES * HEADS * 4);
    float* l1d    = (float*)alloc((size_t)N_NODES * HEADS * 4);
    float* out1   = (float*)alloc((size_t)N_NODES * C1 * 4);
    float* h2     = (float*)alloc((size_t)N_NODES * HID * 4);
    float* l2s    = (float*)alloc((size_t)N_NODES * 4);
    float* l2d    = (float*)alloc((size_t)N_NODES * 4);

    hipMemsetAsync(deg, 0, (size_t)N_NODES * 4, stream);
    k_count<<<(E_TOT + 255) / 256, 256, 0, stream>>>(ei, deg);
    k_scan<<<1, 1024, 0, stream>>>(deg, rowptr, cursor);
    k_scatter<<<(E_TOT + 255) / 256, 256, 0, stream>>>(ei, cursor, csr_src);
    k_gemm1<<<(N_NODES + TM1 - 1) / TM1, 256, 0, stream>>>(x, W1, as1, ad1, h1, l1s, l1d);
    k_agg1<<<N_NODES, 256, 0, stream>>>(h1, l1s, l1d, rowptr, csr_src, b1, out1);
    k_gemm2<<<(N_NODES + TM2 - 1) / TM2, 256, 0, stream>>>(out1, W2, as2, ad2, h2, l2s, l2d);
    k_agg2<<<(N_NODES + 3) / 4, 256, 0, stream>>>(h2, l2s, l2d, rowptr, csr_src, b2, Wl, bl, out);
}

// Round 2
// 410.916 us; speedup vs baseline: 1.4954x; 1.4954x over previous
//
#include <hip/hip_runtime.h>

#define N_NODES 50000
#define N_EDGES 800000
#define E_TOT   850000            // N_EDGES + N_NODES self loops
#define IN_CH   128
#define HID     64
#define HEADS   4
#define C1      256               // HEADS*HID
#define OUT_CH  64
#define NEG_SLOPE 0.2f
#define EPSV    1e-16f

typedef _Float16 half_t;
typedef _Float16 half2_t __attribute__((ext_vector_type(2)));

// ---------------- CSR build (group edges by dst) ----------------
__global__ void k_count(const int* __restrict__ ei, int* __restrict__ deg) {
    int e = blockIdx.x * blockDim.x + threadIdx.x;
    if (e >= E_TOT) return;
    int d = (e < N_EDGES) ? ei[N_EDGES + e] : (e - N_EDGES);
    atomicAdd(&deg[d], 1);
}

__global__ __launch_bounds__(1024) void k_scan(const int* __restrict__ deg,
                                               int* __restrict__ rowptr,
                                               int* __restrict__ cursor) {
    __shared__ int wsum[16];
    __shared__ int carry_s;
    const int tid = threadIdx.x;
    const int lane = tid & 63;
    const int wv = tid >> 6;
    if (tid == 0) carry_s = 0;
    __syncthreads();
    for (int base = 0; base < N_NODES; base += 1024) {
        int i = base + tid;
        int v = (i < N_NODES) ? deg[i] : 0;
        int s = v;
        #pragma unroll
        for (int d = 1; d < 64; d <<= 1) {
            int t = __shfl_up(s, d, 64);
            if (lane >= d) s += t;
        }
        if (lane == 63) wsum[wv] = s;
        __syncthreads();
        if (wv == 0 && lane < 16) {
            int w = wsum[lane];
            #pragma unroll
            for (int d = 1; d < 16; d <<= 1) {
                int t = __shfl_up(w, d, 64);
                if (lane >= d) w += t;
            }
            wsum[lane] = w;
        }
        __syncthreads();
        int excl = carry_s + ((wv > 0) ? wsum[wv - 1] : 0) + (s - v);
        if (i < N_NODES) { rowptr[i] = excl; cursor[i] = excl; }
        __syncthreads();
        if (tid == 0) carry_s += wsum[15];
        __syncthreads();
    }
    if (tid == 0) rowptr[N_NODES] = carry_s;
}

__global__ void k_scatter(const int* __restrict__ ei, int* __restrict__ cursor,
                          int* __restrict__ csr_src) {
    int e = blockIdx.x * blockDim.x + threadIdx.x;
    if (e >= E_TOT) return;
    int s, d;
    if (e < N_EDGES) { s = ei[e]; d = ei[N_EDGES + e]; }
    else             { s = d = e - N_EDGES; }
    int pos = atomicAdd(&cursor[d], 1);
    csr_src[pos] = s;
}

// ---------------- GEMM1: h1 = x @ W1 (fp16 out), fused attention logits ----------------
// 256 thr: 8 rows x 4 cols per thread; 32x256 block tile; LDS x reads are
// wave-uniform broadcasts (r8,k uniform within a wave) -> conflict-free.
#define TM1 32
__global__ __launch_bounds__(256) void k_gemm1(
    const float* __restrict__ x, const float* __restrict__ W1,
    const float* __restrict__ a_s1, const float* __restrict__ a_d1,
    half_t* __restrict__ h1h, float* __restrict__ l1s, float* __restrict__ l1d) {
    __shared__ float xs[TM1 * IN_CH];            // 16 KB
    const int base = blockIdx.x * TM1;
    const int rows = min(TM1, N_NODES - base);
    const int tid = threadIdx.x;
    for (int i = tid; i < TM1 * IN_CH / 4; i += 256) {
        int flat = i * 4;
        int m = flat >> 7;
        float4 v = make_float4(0.f, 0.f, 0.f, 0.f);
        if (m < rows) v = *(const float4*)(x + (size_t)(base + m) * IN_CH + (flat & 127));
        *(float4*)(xs + flat) = v;
    }
    __syncthreads();
    const int lane = tid & 63;
    const int c4 = lane * 4;                     // cols c4..c4+3
    const int r8 = (tid >> 6) * 8;               // rows r8..r8+7 (wave-uniform)
    float acc[8][4];
    #pragma unroll
    for (int i = 0; i < 8; ++i)
        #pragma unroll
        for (int j = 0; j < 4; ++j) acc[i][j] = 0.f;

    for (int k = 0; k < IN_CH; k += 4) {
        float wk[4][4];
        #pragma unroll
        for (int j = 0; j < 4; ++j) {
            float4 w = *(const float4*)(W1 + (size_t)(k + j) * C1 + c4);
            wk[j][0] = w.x; wk[j][1] = w.y; wk[j][2] = w.z; wk[j][3] = w.w;
        }
        #pragma unroll
        for (int i = 0; i < 8; ++i) {
            float4 xv = *(const float4*)(xs + (r8 + i) * IN_CH + k);  // broadcast
            float xk[4] = {xv.x, xv.y, xv.z, xv.w};
            #pragma unroll
            for (int kk = 0; kk < 4; ++kk)
                #pragma unroll
                for (int j = 0; j < 4; ++j)
                    acc[i][j] = fmaf(xk[kk], wk[kk][j], acc[i][j]);
        }
    }

    const float4 asv = *(const float4*)(a_s1 + c4);
    const float4 adv = *(const float4*)(a_d1 + c4);
    for (int i = 0; i < 8; ++i) {
        int m = r8 + i;
        if (m < rows) {                          // wave-uniform guard
            float ps = acc[i][0] * asv.x + acc[i][1] * asv.y + acc[i][2] * asv.z + acc[i][3] * asv.w;
            float pd = acc[i][0] * adv.x + acc[i][1] * adv.y + acc[i][2] * adv.z + acc[i][3] * adv.w;
            #pragma unroll
            for (int d = 1; d < 16; d <<= 1) {   // reduce over the head's 16 lanes
                ps += __shfl_xor(ps, d, 64);
                pd += __shfl_xor(pd, d, 64);
            }
            if ((lane & 15) == 0) {
                int h = lane >> 4;
                l1s[(base + m) * HEADS + h] = ps;
                l1d[(base + m) * HEADS + h] = pd;
            }
            half2_t pa, pb;
            pa[0] = (half_t)acc[i][0]; pa[1] = (half_t)acc[i][1];
            pb[0] = (half_t)acc[i][2]; pb[1] = (half_t)acc[i][3];
            float2 st;
            st.x = __builtin_bit_cast(float, pa);
            st.y = __builtin_bit_cast(float, pb);
            *(float2*)(h1h + (size_t)(base + m) * C1 + c4) = st;
        }
    }
}

// ---------------- agg1: wave per node, fp16 gather, 4 ch/lane ----------------
__global__ __launch_bounds__(256) void k_agg1(
    const half_t* __restrict__ h1h, const float* __restrict__ l1s, const float* __restrict__ l1d,
    const int* __restrict__ rowptr, const int* __restrict__ csr_src,
    const float* __restrict__ b1, float* __restrict__ out1) {
    const int tid = threadIdx.x;
    const int lane = tid & 63;
    const int wv = tid >> 6;
    const int n = blockIdx.x * 4 + wv;
    if (n >= N_NODES) return;                    // no syncthreads below
    const int beg = rowptr[n], end = rowptr[n + 1];
    const float4 ldv = *(const float4*)(l1d + (size_t)n * 4);
    // pass A: per-head max
    float mx0 = -1e30f, mx1 = -1e30f, mx2 = -1e30f, mx3 = -1e30f;
    for (int e = beg + lane; e < end; e += 64) {
        int s = csr_src[e];
        const float4 ls = *(const float4*)(l1s + (size_t)s * 4);
        float e0 = ls.x + ldv.x; e0 = (e0 > 0.f) ? e0 : NEG_SLOPE * e0;
        float e1 = ls.y + ldv.y; e1 = (e1 > 0.f) ? e1 : NEG_SLOPE * e1;
        float e2 = ls.z + ldv.z; e2 = (e2 > 0.f) ? e2 : NEG_SLOPE * e2;
        float e3 = ls.w + ldv.w; e3 = (e3 > 0.f) ? e3 : NEG_SLOPE * e3;
        mx0 = fmaxf(mx0, e0); mx1 = fmaxf(mx1, e1);
        mx2 = fmaxf(mx2, e2); mx3 = fmaxf(mx3, e3);
    }
    #pragma unroll
    for (int d = 1; d < 64; d <<= 1) {
        mx0 = fmaxf(mx0, __shfl_xor(mx0, d, 64));
        mx1 = fmaxf(mx1, __shfl_xor(mx1, d, 64));
        mx2 = fmaxf(mx2, __shfl_xor(mx2, d, 64));
        mx3 = fmaxf(mx3, __shfl_xor(mx3, d, 64));
    }
    const int hh = lane >> 4;
    const float mxh = (hh & 2) ? ((hh & 1) ? mx3 : mx2) : ((hh & 1) ? mx1 : mx0);
    const float ldh = (hh & 2) ? ((hh & 1) ? ldv.w : ldv.z) : ((hh & 1) ? ldv.y : ldv.x);
    const float* l1sh = l1s + hh;
    const float2* hrows = (const float2*)h1h;    // 64 float2 per row
    // pass B: unnormalized accumulate, unroll 2 for ILP
    float a0 = 0.f, a1 = 0.f, a2 = 0.f, a3 = 0.f, dn = 0.f;
    int e = beg;
    for (; e + 1 < end; e += 2) {
        int s0 = csr_src[e], s1 = csr_src[e + 1];
        float2 r0 = hrows[(size_t)s0 * 64 + lane];
        float2 r1 = hrows[(size_t)s1 * 64 + lane];
        float lg0 = l1sh[(size_t)s0 * 4] + ldh;
        float lg1 = l1sh[(size_t)s1 * 4] + ldh;
        lg0 = (lg0 > 0.f) ? lg0 : NEG_SLOPE * lg0;
        lg1 = (lg1 > 0.f) ? lg1 : NEG_SLOPE * lg1;
        float w0 = __expf(lg0 - mxh);
        float w1 = __expf(lg1 - mxh);
        dn += w0 + w1;
        half2_t ha0 = __builtin_bit_cast(half2_t, r0.x);
        half2_t hb0 = __builtin_bit_cast(half2_t, r0.y);
        half2_t ha1 = __builtin_bit_cast(half2_t, r1.x);
        half2_t hb1 = __builtin_bit_cast(half2_t, r1.y);
        a0 = fmaf(w0, (float)ha0[0], a0); a1 = fmaf(w0, (float)ha0[1], a1);
        a2 = fmaf(w0, (float)hb0[0], a2); a3 = fmaf(w0, (float)hb0[1], a3);
        a0 = fmaf(w1, (float)ha1[0], a0); a1 = fmaf(w1, (float)ha1[1], a1);
        a2 = fmaf(w1, (float)hb1[0], a2); a3 = fmaf(w1, (float)hb1[1], a3);
    }
    if (e < end) {
        int s0 = csr_src[e];
        float2 r0 = hrows[(size_t)s0 * 64 + lane];
        float lg0 = l1sh[(size_t)s0 * 4] + ldh;
        lg0 = (lg0 > 0.f) ? lg0 : NEG_SLOPE * lg0;
        float w0 = __expf(lg0 - mxh);
        dn += w0;
        half2_t ha0 = __builtin_bit_cast(half2_t, r0.x);
        half2_t hb0 = __builtin_bit_cast(half2_t, r0.y);
        a0 = fmaf(w0, (float)ha0[0], a0); a1 = fmaf(w0, (float)ha0[1], a1);
        a2 = fmaf(w0, (float)hb0[0], a2); a3 = fmaf(w0, (float)hb0[1], a3);
    }
    const float inv = 1.f / (dn + EPSV);
    const int ch4 = lane * 4;
    const float4 bv = *(const float4*)(b1 + ch4);
    float4 o;
    o.x = fmaxf(fmaf(a0, inv, bv.x), 0.f);
    o.y = fmaxf(fmaf(a1, inv, bv.y), 0.f);
    o.z = fmaxf(fmaf(a2, inv, bv.z), 0.f);
    o.w = fmaxf(fmaf(a3, inv, bv.w), 0.f);
    *(float4*)(out1 + (size_t)n * C1 + ch4) = o;
}

// ---------------- GEMM2: h2 = out1 @ W2 (fp16 out), fused logits (1 head) ----------------
// 256 thr: 4 rows x 4 cols per thread; 64x64 block tile, K=256.
#define TM2 64
#define XS2_LD (C1 + 4)                          // pad: +4 floats -> 2-way max on LDS reads
__global__ __launch_bounds__(256) void k_gemm2(
    const float* __restrict__ xin, const float* __restrict__ W2,
    const float* __restrict__ a_s2, const float* __restrict__ a_d2,
    half_t* __restrict__ h2h, float* __restrict__ l2s, float* __restrict__ l2d) {
    __shared__ float xs[TM2 * XS2_LD];           // 65 KB
    const int base = blockIdx.x * TM2;
    const int rows = min(TM2, N_NODES - base);
    const int tid = threadIdx.x;
    for (int i = tid; i < TM2 * C1 / 4; i += 256) {
        int flat = i * 4;
        int m = flat >> 8;
        int col = flat & 255;
        float4 v = make_float4(0.f, 0.f, 0.f, 0.f);
        if (m < rows) v = *(const float4*)(xin + (size_t)(base + m) * C1 + col);
        *(float4*)(xs + m * XS2_LD + col) = v;
    }
    __syncthreads();
    const int lane = tid & 63;
    const int c4 = (tid & 15) * 4;               // cols c4..c4+3
    const int rg = (tid >> 4) * 4;               // rows rg..rg+3
    float acc[4][4];
    #pragma unroll
    for (int i = 0; i < 4; ++i)
        #pragma unroll
        for (int j = 0; j < 4; ++j) acc[i][j] = 0.f;

    for (int k = 0; k < C1; k += 4) {
        float wk[4][4];
        #pragma unroll
        for (int j = 0; j < 4; ++j) {
            float4 w = *(const float4*)(W2 + (size_t)(k + j) * HID + c4);
            wk[j][0] = w.x; wk[j][1] = w.y; wk[j][2] = w.z; wk[j][3] = w.w;
        }
        #pragma unroll
        for (int i = 0; i < 4; ++i) {
            float4 xv = *(const float4*)(xs + (rg + i) * XS2_LD + k);
            float xk[4] = {xv.x, xv.y, xv.z, xv.w};
            #pragma unroll
            for (int kk = 0; kk < 4; ++kk)
                #pragma unroll
                for (int j = 0; j < 4; ++j)
                    acc[i][j] = fmaf(xk[kk], wk[kk][j], acc[i][j]);
        }
    }

    const float4 asv = *(const float4*)(a_s2 + c4);
    const float4 adv = *(const float4*)(a_d2 + c4);
    for (int i = 0; i < 4; ++i) {
        int m = rg + i;
        if (m < rows) {                          // uniform within each 16-lane group
            float ps = acc[i][0] * asv.x + acc[i][1] * asv.y + acc[i][2] * asv.z + acc[i][3] * asv.w;
            float pd = acc[i][0] * adv.x + acc[i][1] * adv.y + acc[i][2] * adv.z + acc[i][3] * adv.w;
            #pragma unroll
            for (int d = 1; d < 16; d <<= 1) {
                ps += __shfl_xor(ps, d, 64);
                pd += __shfl_xor(pd, d, 64);
            }
            if ((lane & 15) == 0) {
                l2s[base + m] = ps;
                l2d[base + m] = pd;
            }
            half2_t pa, pb;
            pa[0] = (half_t)acc[i][0]; pa[1] = (half_t)acc[i][1];
            pb[0] = (half_t)acc[i][2]; pb[1] = (half_t)acc[i][3];
            float2 st;
            st.x = __builtin_bit_cast(float, pa);
            st.y = __builtin_bit_cast(float, pb);
            *(float2*)(h2h + (size_t)(base + m) * HID + c4) = st;
        }
    }
}

// ---------------- agg2 + final linear: wave per node, 2 edges in parallel ----------------
__global__ __launch_bounds__(256) void k_agg2(
    const half_t* __restrict__ h2h, const float* __restrict__ l2s, const float* __restrict__ l2d,
    const int* __restrict__ rowptr, const int* __restrict__ csr_src,
    const float* __restrict__ b2, const float* __restrict__ Wl, const float* __restrict__ bl,
    float* __restrict__ out) {
    __shared__ float Wls[HID * OUT_CH];          // 16 KB
    __shared__ float vsh[4][HID];
    const int tid = threadIdx.x;
    const int lane = tid & 63;
    const int wv = tid >> 6;
    for (int i = tid; i < HID * OUT_CH; i += 256) Wls[i] = Wl[i];
    const int n = blockIdx.x * 4 + wv;
    const bool active = (n < N_NODES);
    if (active) {
        const int beg = rowptr[n], end = rowptr[n + 1];
        const float ld = l2d[n];
        float mx = -1e30f;
        for (int e = beg + lane; e < end; e += 64) {
            float lg = l2s[csr_src[e]] + ld;
            lg = (lg > 0.f) ? lg : NEG_SLOPE * lg;
            mx = fmaxf(mx, lg);
        }
        #pragma unroll
        for (int d = 1; d < 64; d <<= 1) mx = fmaxf(mx, __shfl_xor(mx, d, 64));
        // half-wave per edge; each lane covers 2 channels
        const int eo = lane >> 5;
        const int ch2 = (lane & 31) * 2;
        float a0 = 0.f, a1 = 0.f, dn = 0.f;
        for (int e = beg + eo; e < end; e += 2) {
            int s = csr_src[e];
            float lg = l2s[s] + ld;
            lg = (lg > 0.f) ? lg : NEG_SLOPE * lg;
            float w = __expf(lg - mx);
            dn += w;
            half2_t hv = ((const half2_t*)(h2h + (size_t)s * HID))[lane & 31];
            a0 = fmaf(w, (float)hv[0], a0);
            a1 = fmaf(w, (float)hv[1], a1);
        }
        a0 += __shfl_xor(a0, 32, 64);
        a1 += __shfl_xor(a1, 32, 64);
        dn += __shfl_xor(dn, 32, 64);
        if (eo == 0) {
            float inv = 1.f / (dn + EPSV);
            vsh[wv][ch2]     = fmaf(a0, inv, b2[ch2]);
            vsh[wv][ch2 + 1] = fmaf(a1, inv, b2[ch2 + 1]);
        }
    }
    __syncthreads();
    if (active) {
        float o = bl[lane];
        #pragma unroll
        for (int c2 = 0; c2 < HID; ++c2)
            o = fmaf(vsh[wv][c2], Wls[c2 * OUT_CH + lane], o);
        out[(size_t)n * OUT_CH + lane] = o;
    }
}

extern "C" void kernel_launch(void* const* d_in, const int* in_sizes, int n_in,
                              void* d_out, int out_size, void* d_ws, size_t ws_size,
                              hipStream_t stream) {
    const float* x   = (const float*)d_in[0];
    const int*   ei  = (const int*)d_in[1];
    const float* W1  = (const float*)d_in[2];
    const float* as1 = (const float*)d_in[3];
    const float* ad1 = (const float*)d_in[4];
    const float* b1  = (const float*)d_in[5];
    const float* W2  = (const float*)d_in[6];
    const float* as2 = (const float*)d_in[7];
    const float* ad2 = (const float*)d_in[8];
    const float* b2  = (const float*)d_in[9];
    const float* Wl  = (const float*)d_in[10];
    const float* bl  = (const float*)d_in[11];
    float* out = (float*)d_out;

    char* p = (char*)d_ws;
    auto alloc = [&](size_t bytes) {
        char* r = p;
        p += (bytes + 255) & ~(size_t)255;
        return r;
    };
    int* deg      = (int*)alloc((size_t)N_NODES * 4);
    int* rowptr   = (int*)alloc((size_t)(N_NODES + 1) * 4);
    int* cursor   = (int*)alloc((size_t)N_NODES * 4);
    int* csr_src  = (int*)alloc((size_t)E_TOT * 4);
    half_t* h1h   = (half_t*)alloc((size_t)N_NODES * C1 * 2);
    float* l1s    = (float*)alloc((size_t)N_NODES * HEADS * 4);
    float* l1d    = (float*)alloc((size_t)N_NODES * HEADS * 4);
    float* out1   = (float*)alloc((size_t)N_NODES * C1 * 4);
    half_t* h2h   = (half_t*)alloc((size_t)N_NODES * HID * 2);
    float* l2s    = (float*)alloc((size_t)N_NODES * 4);
    float* l2d    = (float*)alloc((size_t)N_NODES * 4);

    hipMemsetAsync(deg, 0, (size_t)N_NODES * 4, stream);
    k_count<<<(E_TOT + 255) / 256, 256, 0, stream>>>(ei, deg);
    k_scan<<<1, 1024, 0, stream>>>(deg, rowptr, cursor);
    k_scatter<<<(E_TOT + 255) / 256, 256, 0, stream>>>(ei, cursor, csr_src);
    k_gemm1<<<(N_NODES + TM1 - 1) / TM1, 256, 0, stream>>>(x, W1, as1, ad1, h1h, l1s, l1d);
    k_agg1<<<(N_NODES + 3) / 4, 256, 0, stream>>>(h1h, l1s, l1d, rowptr, csr_src, b1, out1);
    k_gemm2<<<(N_NODES + TM2 - 1) / TM2, 256, 0, stream>>>(out1, W2, as2, ad2, h2h, l2s, l2d);
    k_agg2<<<(N_NODES + 3) / 4, 256, 0, stream>>>(h2h, l2s, l2d, rowptr, csr_src, b2, Wl, bl, out);
}

// Round 4
// 291.173 us; speedup vs baseline: 2.1104x; 1.4112x over previous
//
#include <hip/hip_runtime.h>

#define N_NODES 50000
#define N_EDGES 800000
#define E_TOT   850000            // N_EDGES + N_NODES self loops
#define IN_CH   128
#define HID     64
#define HEADS   4
#define C1      256               // HEADS*HID
#define OUT_CH  64
#define NEG_SLOPE 0.2f
#define EPSV    1e-16f

typedef _Float16 half_t;
typedef _Float16 half2_t __attribute__((ext_vector_type(2)));
typedef _Float16 half8_t __attribute__((ext_vector_type(8)));
typedef float f32x4 __attribute__((ext_vector_type(4)));

// ---------------- weight prep: W1 -> W1T fp16 [256][128], W2 -> W2T fp16 [64][256] ----------------
__global__ __launch_bounds__(256) void k_prep(const float* __restrict__ W1,
                                              const float* __restrict__ W2,
                                              half_t* __restrict__ W1T,
                                              half_t* __restrict__ W2T) {
    int i = blockIdx.x * 256 + threadIdx.x;
    if (i < IN_CH * C1) {
        int c = i >> 7, k = i & 127;
        W1T[i] = (half_t)W1[k * C1 + c];
    }
    int j = i - IN_CH * C1;
    if (j >= 0 && j < C1 * HID) {
        int c = j >> 8, k = j & 255;
        W2T[j] = (half_t)W2[k * HID + c];
    }
}

// ---------------- CSR build (group edges by dst) ----------------
__global__ void k_count(const int* __restrict__ ei, int* __restrict__ deg) {
    int e = blockIdx.x * blockDim.x + threadIdx.x;
    if (e >= E_TOT) return;
    int d = (e < N_EDGES) ? ei[N_EDGES + e] : (e - N_EDGES);
    atomicAdd(&deg[d], 1);
}

#define SCAN_CH 1024
#define NB_SCAN ((N_NODES + SCAN_CH - 1) / SCAN_CH)   // 49

__global__ __launch_bounds__(256) void k_bsum(const int* __restrict__ deg,
                                              int* __restrict__ bsum) {
    const int b = blockIdx.x;
    const int tid = threadIdx.x;
    int sum = 0;
    for (int i = tid; i < SCAN_CH; i += 256) {
        int idx = b * SCAN_CH + i;
        sum += (idx < N_NODES) ? deg[idx] : 0;
    }
    #pragma unroll
    for (int d = 1; d < 64; d <<= 1) sum += __shfl_xor(sum, d, 64);
    __shared__ int ws[4];
    if ((tid & 63) == 0) ws[tid >> 6] = sum;
    __syncthreads();
    if (tid == 0) bsum[b] = ws[0] + ws[1] + ws[2] + ws[3];
}

__global__ void k_bscan(const int* __restrict__ bsum, int* __restrict__ boff,
                        int* __restrict__ rowptr) {
    int tid = threadIdx.x;                        // 64 threads, 1 block
    int v = (tid < NB_SCAN) ? bsum[tid] : 0;
    int s = v;
    #pragma unroll
    for (int d = 1; d < 64; d <<= 1) {
        int t = __shfl_up(s, d, 64);
        if (tid >= d) s += t;
    }
    boff[tid] = s - v;
    if (tid == 0) rowptr[N_NODES] = E_TOT;
}

__global__ __launch_bounds__(1024) void k_scanf(const int* __restrict__ deg,
                                                const int* __restrict__ boff,
                                                int* __restrict__ rowptr,
                                                int* __restrict__ cursor) {
    const int b = blockIdx.x;
    const int tid = threadIdx.x;
    const int lane = tid & 63;
    const int wv = tid >> 6;                      // 16 waves
    const int i = b * SCAN_CH + tid;
    int v = (i < N_NODES) ? deg[i] : 0;
    int s = v;
    #pragma unroll
    for (int d = 1; d < 64; d <<= 1) {
        int t = __shfl_up(s, d, 64);
        if (lane >= d) s += t;
    }
    __shared__ int wsum[16];
    if (lane == 63) wsum[wv] = s;
    __syncthreads();
    if (wv == 0 && lane < 16) {
        int w = wsum[lane];
        #pragma unroll
        for (int d = 1; d < 16; d <<= 1) {
            int t = __shfl_up(w, d, 64);
            if (lane >= d) w += t;
        }
        wsum[lane] = w;
    }
    __syncthreads();
    int excl = boff[b] + ((wv > 0) ? wsum[wv - 1] : 0) + (s - v);
    if (i < N_NODES) { rowptr[i] = excl; cursor[i] = excl; }
}

__global__ void k_scatter(const int* __restrict__ ei, int* __restrict__ cursor,
                          int* __restrict__ csr_src) {
    int e = blockIdx.x * blockDim.x + threadIdx.x;
    if (e >= E_TOT) return;
    int s, d;
    if (e < N_EDGES) { s = ei[e]; d = ei[N_EDGES + e]; }
    else             { s = d = e - N_EDGES; }
    int pos = atomicAdd(&cursor[d], 1);
    csr_src[pos] = s;
}

// ---------------- GEMM1 (MFMA fp16): h1 = x @ W1, 32x256 tile, K=128 ----------------
#define XS1_LD 136
#define HS1_LD 264
__global__ __launch_bounds__(256) void k_gemm1(
    const float* __restrict__ x, const half_t* __restrict__ W1T,
    half_t* __restrict__ h1h) {
    __shared__ half_t xs[32 * XS1_LD];            // 8.7 KB
    __shared__ half_t hs[32 * HS1_LD];            // 16.9 KB
    const int base = blockIdx.x * 32;
    const int rows = min(32, N_NODES - base);
    const int tid = threadIdx.x;
    // stage x tile as fp16
    for (int idx = tid; idx < 32 * 16; idx += 256) {
        int row = idx >> 4, c8 = (idx & 15) * 8;
        half8_t hv = {0, 0, 0, 0, 0, 0, 0, 0};
        if (row < rows) {
            const float4 v0 = *(const float4*)(x + (size_t)(base + row) * IN_CH + c8);
            const float4 v1 = *(const float4*)(x + (size_t)(base + row) * IN_CH + c8 + 4);
            hv[0] = (half_t)v0.x; hv[1] = (half_t)v0.y; hv[2] = (half_t)v0.z; hv[3] = (half_t)v0.w;
            hv[4] = (half_t)v1.x; hv[5] = (half_t)v1.y; hv[6] = (half_t)v1.z; hv[7] = (half_t)v1.w;
        }
        *(half8_t*)(xs + row * XS1_LD + c8) = hv;
    }
    __syncthreads();
    const int lane = tid & 63;
    const int w = tid >> 6;
    const int cw = w * 64;                        // wave's 64-col slice
    const int lr = lane & 15;
    const int lg = lane >> 4;
    f32x4 acc[2][4];
    #pragma unroll
    for (int i = 0; i < 2; ++i)
        #pragma unroll
        for (int j = 0; j < 4; ++j)
            #pragma unroll
            for (int r = 0; r < 4; ++r) acc[i][j][r] = 0.f;

    #pragma unroll
    for (int kt = 0; kt < 4; ++kt) {
        const int k0 = kt * 32 + lg * 8;
        half8_t A0 = *(const half8_t*)(xs + lr * XS1_LD + k0);
        half8_t A1 = *(const half8_t*)(xs + (16 + lr) * XS1_LD + k0);
        #pragma unroll
        for (int ct = 0; ct < 4; ++ct) {
            half8_t B = *(const half8_t*)(W1T + (size_t)(cw + ct * 16 + lr) * IN_CH + k0);
            acc[0][ct] = __builtin_amdgcn_mfma_f32_16x16x32_f16(A0, B, acc[0][ct], 0, 0, 0);
            acc[1][ct] = __builtin_amdgcn_mfma_f32_16x16x32_f16(A1, B, acc[1][ct], 0, 0, 0);
        }
    }
    // C layout: col = lane&15, row = (lane>>4)*4 + r  -> LDS transpose, coalesced store
    #pragma unroll
    for (int rt = 0; rt < 2; ++rt)
        #pragma unroll
        for (int ct = 0; ct < 4; ++ct)
            #pragma unroll
            for (int r = 0; r < 4; ++r)
                hs[(rt * 16 + lg * 4 + r) * HS1_LD + cw + ct * 16 + lr] = (half_t)acc[rt][ct][r];
    __syncthreads();
    for (int idx = tid; idx < 32 * 32; idx += 256) {
        int row = idx >> 5, c8 = (idx & 31) * 8;
        if (row < rows)
            *(float4*)(h1h + (size_t)(base + row) * C1 + c8) = *(const float4*)(hs + row * HS1_LD + c8);
    }
}

// ---------------- logits1: l1s/l1d = h1 . a  (wave per node) ----------------
__global__ __launch_bounds__(256) void k_logit1(
    const half_t* __restrict__ h1h, const float* __restrict__ a_s1, const float* __restrict__ a_d1,
    float* __restrict__ l1s, float* __restrict__ l1d) {
    const int tid = threadIdx.x;
    const int n = blockIdx.x * 4 + (tid >> 6);
    if (n >= N_NODES) return;
    const int lane = tid & 63;
    const int c4 = lane * 4;
    float2 r = *(const float2*)(h1h + (size_t)n * C1 + c4);
    half2_t ha = __builtin_bit_cast(half2_t, r.x);
    half2_t hb = __builtin_bit_cast(half2_t, r.y);
    const float4 av = *(const float4*)(a_s1 + c4);
    const float4 dv = *(const float4*)(a_d1 + c4);
    float ps = (float)ha[0] * av.x + (float)ha[1] * av.y + (float)hb[0] * av.z + (float)hb[1] * av.w;
    float pd = (float)ha[0] * dv.x + (float)ha[1] * dv.y + (float)hb[0] * dv.z + (float)hb[1] * dv.w;
    #pragma unroll
    for (int d = 1; d < 16; d <<= 1) {
        ps += __shfl_xor(ps, d, 64);
        pd += __shfl_xor(pd, d, 64);
    }
    if ((lane & 15) == 0) {
        int h = lane >> 4;
        l1s[n * HEADS + h] = ps;
        l1d[n * HEADS + h] = pd;
    }
}

// ---------------- agg1: wave per node, fp16 gather, no max pass ----------------
__global__ __launch_bounds__(256) void k_agg1(
    const half_t* __restrict__ h1h, const float* __restrict__ l1s, const float* __restrict__ l1d,
    const int* __restrict__ rowptr, const int* __restrict__ csr_src,
    const float* __restrict__ b1, half_t* __restrict__ out1h) {
    const int tid = threadIdx.x;
    const int lane = tid & 63;
    const int wv = tid >> 6;
    const int n = blockIdx.x * 4 + wv;
    if (n >= N_NODES) return;                     // no syncthreads below
    const int beg = rowptr[n], end = rowptr[n + 1];
    const float4 ldv = *(const float4*)(l1d + (size_t)n * 4);
    const int hh = lane >> 4;
    const float ldh = (hh & 2) ? ((hh & 1) ? ldv.w : ldv.z) : ((hh & 1) ? ldv.y : ldv.x);
    const float* l1sh = l1s + hh;
    const float2* hrows = (const float2*)h1h;     // 64 float2 per row
    float a0 = 0.f, a1 = 0.f, a2 = 0.f, a3 = 0.f, dn = 0.f;
    int e = beg;
    for (; e + 3 < end; e += 4) {
        int s0 = csr_src[e], s1 = csr_src[e + 1], s2 = csr_src[e + 2], s3 = csr_src[e + 3];
        float2 r0 = hrows[(size_t)s0 * 64 + lane];
        float2 r1 = hrows[(size_t)s1 * 64 + lane];
        float2 r2 = hrows[(size_t)s2 * 64 + lane];
        float2 r3 = hrows[(size_t)s3 * 64 + lane];
        float g0 = l1sh[(size_t)s0 * 4] + ldh;
        float g1 = l1sh[(size_t)s1 * 4] + ldh;
        float g2 = l1sh[(size_t)s2 * 4] + ldh;
        float g3 = l1sh[(size_t)s3 * 4] + ldh;
        g0 = (g0 > 0.f) ? g0 : NEG_SLOPE * g0;
        g1 = (g1 > 0.f) ? g1 : NEG_SLOPE * g1;
        g2 = (g2 > 0.f) ? g2 : NEG_SLOPE * g2;
        g3 = (g3 > 0.f) ? g3 : NEG_SLOPE * g3;
        float w0 = __expf(g0), w1 = __expf(g1), w2 = __expf(g2), w3 = __expf(g3);
        dn += (w0 + w1) + (w2 + w3);
        half2_t p;
        p = __builtin_bit_cast(half2_t, r0.x); a0 = fmaf(w0, (float)p[0], a0); a1 = fmaf(w0, (float)p[1], a1);
        p = __builtin_bit_cast(half2_t, r0.y); a2 = fmaf(w0, (float)p[0], a2); a3 = fmaf(w0, (float)p[1], a3);
        p = __builtin_bit_cast(half2_t, r1.x); a0 = fmaf(w1, (float)p[0], a0); a1 = fmaf(w1, (float)p[1], a1);
        p = __builtin_bit_cast(half2_t, r1.y); a2 = fmaf(w1, (float)p[0], a2); a3 = fmaf(w1, (float)p[1], a3);
        p = __builtin_bit_cast(half2_t, r2.x); a0 = fmaf(w2, (float)p[0], a0); a1 = fmaf(w2, (float)p[1], a1);
        p = __builtin_bit_cast(half2_t, r2.y); a2 = fmaf(w2, (float)p[0], a2); a3 = fmaf(w2, (float)p[1], a3);
        p = __builtin_bit_cast(half2_t, r3.x); a0 = fmaf(w3, (float)p[0], a0); a1 = fmaf(w3, (float)p[1], a1);
        p = __builtin_bit_cast(half2_t, r3.y); a2 = fmaf(w3, (float)p[0], a2); a3 = fmaf(w3, (float)p[1], a3);
    }
    for (; e < end; ++e) {
        int s0 = csr_src[e];
        float2 r0 = hrows[(size_t)s0 * 64 + lane];
        float g0 = l1sh[(size_t)s0 * 4] + ldh;
        g0 = (g0 > 0.f) ? g0 : NEG_SLOPE * g0;
        float w0 = __expf(g0);
        dn += w0;
        half2_t p;
        p = __builtin_bit_cast(half2_t, r0.x); a0 = fmaf(w0, (float)p[0], a0); a1 = fmaf(w0, (float)p[1], a1);
        p = __builtin_bit_cast(half2_t, r0.y); a2 = fmaf(w0, (float)p[0], a2); a3 = fmaf(w0, (float)p[1], a3);
    }
    const float inv = 1.f / (dn + EPSV);
    const int c4 = lane * 4;
    const float4 bv = *(const float4*)(b1 + c4);
    half2_t pa, pb;
    pa[0] = (half_t)fmaxf(fmaf(a0, inv, bv.x), 0.f);
    pa[1] = (half_t)fmaxf(fmaf(a1, inv, bv.y), 0.f);
    pb[0] = (half_t)fmaxf(fmaf(a2, inv, bv.z), 0.f);
    pb[1] = (half_t)fmaxf(fmaf(a3, inv, bv.w), 0.f);
    float2 st;
    st.x = __builtin_bit_cast(float, pa);
    st.y = __builtin_bit_cast(float, pb);
    *(float2*)(out1h + (size_t)n * C1 + c4) = st;
}

// ---------------- GEMM2 (MFMA fp16): h2 = out1 @ W2, 32x64 tile, K=256 ----------------
#define XS2_LD 264
#define HS2_LD 72
__global__ __launch_bounds__(256) void k_gemm2(
    const half_t* __restrict__ out1h, const half_t* __restrict__ W2T,
    half_t* __restrict__ h2h) {
    __shared__ half_t xs[32 * XS2_LD];            // 16.9 KB
    __shared__ half_t hs[32 * HS2_LD];            // 4.6 KB
    const int base = blockIdx.x * 32;
    const int rows = min(32, N_NODES - base);
    const int tid = threadIdx.x;
    for (int idx = tid; idx < 32 * 32; idx += 256) {
        int row = idx >> 5, c8 = (idx & 31) * 8;
        half8_t hv = {0, 0, 0, 0, 0, 0, 0, 0};
        if (row < rows) hv = *(const half8_t*)(out1h + (size_t)(base + row) * C1 + c8);
        *(half8_t*)(xs + row * XS2_LD + c8) = hv;
    }
    __syncthreads();
    const int lane = tid & 63;
    const int w = tid >> 6;                       // wave w -> cols 16w..16w+15
    const int lr = lane & 15;
    const int lg = lane >> 4;
    f32x4 acc0, acc1;
    #pragma unroll
    for (int r = 0; r < 4; ++r) { acc0[r] = 0.f; acc1[r] = 0.f; }
    #pragma unroll
    for (int kt = 0; kt < 8; ++kt) {
        const int k0 = kt * 32 + lg * 8;
        half8_t A0 = *(const half8_t*)(xs + lr * XS2_LD + k0);
        half8_t A1 = *(const half8_t*)(xs + (16 + lr) * XS2_LD + k0);
        half8_t B  = *(const half8_t*)(W2T + (size_t)(w * 16 + lr) * C1 + k0);
        acc0 = __builtin_amdgcn_mfma_f32_16x16x32_f16(A0, B, acc0, 0, 0, 0);
        acc1 = __builtin_amdgcn_mfma_f32_16x16x32_f16(A1, B, acc1, 0, 0, 0);
    }
    #pragma unroll
    for (int r = 0; r < 4; ++r) {
        hs[(lg * 4 + r) * HS2_LD + w * 16 + lr] = (half_t)acc0[r];
        hs[(16 + lg * 4 + r) * HS2_LD + w * 16 + lr] = (half_t)acc1[r];
    }
    __syncthreads();
    {
        int idx = tid;                            // 32 rows x 8 chunks == 256
        int row = idx >> 3, c8 = (idx & 7) * 8;
        if (row < rows)
            *(float4*)(h2h + (size_t)(base + row) * HID + c8) = *(const float4*)(hs + row * HS2_LD + c8);
    }
}

// ---------------- logits2 (1 head, wave per node) ----------------
__global__ __launch_bounds__(256) void k_logit2(
    const half_t* __restrict__ h2h, const float* __restrict__ a_s2, const float* __restrict__ a_d2,
    float* __restrict__ l2s, float* __restrict__ l2d) {
    const int tid = threadIdx.x;
    const int n = blockIdx.x * 4 + (tid >> 6);
    if (n >= N_NODES) return;
    const int lane = tid & 63;
    float v = (float)h2h[(size_t)n * HID + lane];
    float ps = v * a_s2[lane];
    float pd = v * a_d2[lane];
    #pragma unroll
    for (int d = 1; d < 64; d <<= 1) {
        ps += __shfl_xor(ps, d, 64);
        pd += __shfl_xor(pd, d, 64);
    }
    if (lane == 0) { l2s[n] = ps; l2d[n] = pd; }
}

// ---------------- agg2 + final linear: wave per node, no max pass ----------------
__global__ __launch_bounds__(256) void k_agg2(
    const half_t* __restrict__ h2h, const float* __restrict__ l2s, const float* __restrict__ l2d,
    const int* __restrict__ rowptr, const int* __restrict__ csr_src,
    const float* __restrict__ b2, const float* __restrict__ Wl, const float* __restrict__ bl,
    float* __restrict__ out) {
    __shared__ float Wls[HID * OUT_CH];           // 16 KB
    __shared__ float vsh[4][HID];
    const int tid = threadIdx.x;
    const int lane = tid & 63;
    const int wv = tid >> 6;
    for (int i = tid; i < HID * OUT_CH; i += 256) Wls[i] = Wl[i];
    const int n = blockIdx.x * 4 + wv;
    const bool active = (n < N_NODES);
    if (active) {
        const int beg = rowptr[n], end = rowptr[n + 1];
        const float ld = l2d[n];
        // half-wave per edge; each lane covers 2 channels
        const int eo = lane >> 5;
        const int ch2 = (lane & 31) * 2;
        float a0 = 0.f, a1 = 0.f, dn = 0.f;
        for (int e = beg + eo; e < end; e += 2) {
            int s = csr_src[e];
            float lg = l2s[s] + ld;
            lg = (lg > 0.f) ? lg : NEG_SLOPE * lg;
            float w = __expf(lg);
            dn += w;
            half2_t hv = ((const half2_t*)(h2h + (size_t)s * HID))[lane & 31];
            a0 = fmaf(w, (float)hv[0], a0);
            a1 = fmaf(w, (float)hv[1], a1);
        }
        a0 += __shfl_xor(a0, 32, 64);
        a1 += __shfl_xor(a1, 32, 64);
        dn += __shfl_xor(dn, 32, 64);
        if (eo == 0) {
            float inv = 1.f / (dn + EPSV);
            vsh[wv][ch2]     = fmaf(a0, inv, b2[ch2]);
            vsh[wv][ch2 + 1] = fmaf(a1, inv, b2[ch2 + 1]);
        }
    }
    __syncthreads();
    if (active) {
        float o = bl[lane];
        #pragma unroll
        for (int c2 = 0; c2 < HID; ++c2)
            o = fmaf(vsh[wv][c2], Wls[c2 * OUT_CH + lane], o);
        out[(size_t)n * OUT_CH + lane] = o;
    }
}

extern "C" void kernel_launch(void* const* d_in, const int* in_sizes, int n_in,
                              void* d_out, int out_size, void* d_ws, size_t ws_size,
                              hipStream_t stream) {
    const float* x   = (const float*)d_in[0];
    const int*   ei  = (const int*)d_in[1];
    const float* W1  = (const float*)d_in[2];
    const float* as1 = (const float*)d_in[3];
    const float* ad1 = (const float*)d_in[4];
    const float* b1  = (const float*)d_in[5];
    const float* W2  = (const float*)d_in[6];
    const float* as2 = (const float*)d_in[7];
    const float* ad2 = (const float*)d_in[8];
    const float* b2  = (const float*)d_in[9];
    const float* Wl  = (const float*)d_in[10];
    const float* bl  = (const float*)d_in[11];
    float* out = (float*)d_out;

    char* p = (char*)d_ws;
    auto alloc = [&](size_t bytes) {
        char* r = p;
        p += (bytes + 255) & ~(size_t)255;
        return r;
    };
    int* deg      = (int*)alloc((size_t)N_NODES * 4);
    int* rowptr   = (int*)alloc((size_t)(N_NODES + 1) * 4);
    int* cursor   = (int*)alloc((size_t)N_NODES * 4);
    int* csr_src  = (int*)alloc((size_t)E_TOT * 4);
    int* bsum     = (int*)alloc(64 * 4);
    int* boff     = (int*)alloc(64 * 4);
    half_t* W1T   = (half_t*)alloc((size_t)IN_CH * C1 * 2);
    half_t* W2T   = (half_t*)alloc((size_t)C1 * HID * 2);
    half_t* h1h   = (half_t*)alloc((size_t)N_NODES * C1 * 2);
    float* l1s    = (float*)alloc((size_t)N_NODES * HEADS * 4);
    float* l1d    = (float*)alloc((size_t)N_NODES * HEADS * 4);
    half_t* out1h = (half_t*)alloc((size_t)N_NODES * C1 * 2);
    half_t* h2h   = (half_t*)alloc((size_t)N_NODES * HID * 2);
    float* l2s    = (float*)alloc((size_t)N_NODES * 4);
    float* l2d    = (float*)alloc((size_t)N_NODES * 4);

    (void)hipMemsetAsync(deg, 0, (size_t)N_NODES * 4, stream);
    k_prep<<<(IN_CH * C1 + C1 * HID + 255) / 256, 256, 0, stream>>>(W1, W2, W1T, W2T);
    k_count<<<(E_TOT + 255) / 256, 256, 0, stream>>>(ei, deg);
    k_bsum<<<NB_SCAN, 256, 0, stream>>>(deg, bsum);
    k_bscan<<<1, 64, 0, stream>>>(bsum, boff, rowptr);
    k_scanf<<<NB_SCAN, 1024, 0, stream>>>(deg, boff, rowptr, cursor);
    k_scatter<<<(E_TOT + 255) / 256, 256, 0, stream>>>(ei, cursor, csr_src);
    k_gemm1<<<(N_NODES + 31) / 32, 256, 0, stream>>>(x, W1T, h1h);
    k_logit1<<<(N_NODES + 3) / 4, 256, 0, stream>>>(h1h, as1, ad1, l1s, l1d);
    k_agg1<<<(N_NODES + 3) / 4, 256, 0, stream>>>(h1h, l1s, l1d, rowptr, csr_src, b1, out1h);
    k_gemm2<<<(N_NODES + 31) / 32, 256, 0, stream>>>(out1h, W2T, h2h);
    k_logit2<<<(N_NODES + 3) / 4, 256, 0, stream>>>(h2h, as2, ad2, l2s, l2d);
    k_agg2<<<(N_NODES + 3) / 4, 256, 0, stream>>>(h2h, l2s, l2d, rowptr, csr_src, b2, Wl, bl, out);
}

// Round 5
// 267.706 us; speedup vs baseline: 2.2953x; 1.0877x over previous
//
#include <hip/hip_runtime.h>

#define N_NODES 50000
#define N_EDGES 800000
#define E_TOT   850000            // N_EDGES + N_NODES self loops
#define IN_CH   128
#define HID     64
#define HEADS   4
#define C1      256               // HEADS*HID
#define OUT_CH  64
#define NEG_SLOPE 0.2f
#define EPSV    1e-16f

typedef _Float16 half_t;
typedef _Float16 half2_t __attribute__((ext_vector_type(2)));
typedef _Float16 half8_t __attribute__((ext_vector_type(8)));
typedef float f32x4 __attribute__((ext_vector_type(4)));

// ---------------- weight prep: W1 -> W1T fp16 [256][128], W2 -> W2T fp16 [64][256] ----------------
__global__ __launch_bounds__(256) void k_prep(const float* __restrict__ W1,
                                              const float* __restrict__ W2,
                                              half_t* __restrict__ W1T,
                                              half_t* __restrict__ W2T) {
    int i = blockIdx.x * 256 + threadIdx.x;
    if (i < IN_CH * C1) {
        int c = i >> 7, k = i & 127;
        W1T[i] = (half_t)W1[k * C1 + c];
    }
    int j = i - IN_CH * C1;
    if (j >= 0 && j < C1 * HID) {
        int c = j >> 8, k = j & 255;
        W2T[j] = (half_t)W2[k * HID + c];
    }
}

// ---------------- CSR build (group edges by dst) ----------------
__global__ void k_count(const int* __restrict__ ei, int* __restrict__ deg) {
    int e = blockIdx.x * blockDim.x + threadIdx.x;
    if (e >= E_TOT) return;
    int d = (e < N_EDGES) ? ei[N_EDGES + e] : (e - N_EDGES);
    atomicAdd(&deg[d], 1);
}

#define SCAN_CH 1024
#define NB_SCAN ((N_NODES + SCAN_CH - 1) / SCAN_CH)   // 49

__global__ __launch_bounds__(256) void k_bsum(const int* __restrict__ deg,
                                              int* __restrict__ bsum) {
    const int b = blockIdx.x;
    const int tid = threadIdx.x;
    int sum = 0;
    for (int i = tid; i < SCAN_CH; i += 256) {
        int idx = b * SCAN_CH + i;
        sum += (idx < N_NODES) ? deg[idx] : 0;
    }
    #pragma unroll
    for (int d = 1; d < 64; d <<= 1) sum += __shfl_xor(sum, d, 64);
    __shared__ int ws[4];
    if ((tid & 63) == 0) ws[tid >> 6] = sum;
    __syncthreads();
    if (tid == 0) bsum[b] = ws[0] + ws[1] + ws[2] + ws[3];
}

__global__ void k_bscan(const int* __restrict__ bsum, int* __restrict__ boff,
                        int* __restrict__ rowptr) {
    int tid = threadIdx.x;                        // 64 threads, 1 block
    int v = (tid < NB_SCAN) ? bsum[tid] : 0;
    int s = v;
    #pragma unroll
    for (int d = 1; d < 64; d <<= 1) {
        int t = __shfl_up(s, d, 64);
        if (tid >= d) s += t;
    }
    boff[tid] = s - v;
    if (tid == 0) rowptr[N_NODES] = E_TOT;
}

__global__ __launch_bounds__(1024) void k_scanf(const int* __restrict__ deg,
                                                const int* __restrict__ boff,
                                                int* __restrict__ rowptr,
                                                int* __restrict__ cursor) {
    const int b = blockIdx.x;
    const int tid = threadIdx.x;
    const int lane = tid & 63;
    const int wv = tid >> 6;                      // 16 waves
    const int i = b * SCAN_CH + tid;
    int v = (i < N_NODES) ? deg[i] : 0;
    int s = v;
    #pragma unroll
    for (int d = 1; d < 64; d <<= 1) {
        int t = __shfl_up(s, d, 64);
        if (lane >= d) s += t;
    }
    __shared__ int wsum[16];
    if (lane == 63) wsum[wv] = s;
    __syncthreads();
    if (wv == 0 && lane < 16) {
        int w = wsum[lane];
        #pragma unroll
        for (int d = 1; d < 16; d <<= 1) {
            int t = __shfl_up(w, d, 64);
            if (lane >= d) w += t;
        }
        wsum[lane] = w;
    }
    __syncthreads();
    int excl = boff[b] + ((wv > 0) ? wsum[wv - 1] : 0) + (s - v);
    if (i < N_NODES) { rowptr[i] = excl; cursor[i] = excl; }
}

__global__ void k_scatter(const int* __restrict__ ei, int* __restrict__ cursor,
                          int* __restrict__ csr_src) {
    int e = blockIdx.x * blockDim.x + threadIdx.x;
    if (e >= E_TOT) return;
    int s, d;
    if (e < N_EDGES) { s = ei[e]; d = ei[N_EDGES + e]; }
    else             { s = d = e - N_EDGES; }
    int pos = atomicAdd(&cursor[d], 1);
    csr_src[pos] = s;
}

// ---------------- GEMM1 (MFMA fp16): h1 = x @ W1, 32x256 tile, K=128; fused logits ----------------
#define XS1_LD 136
#define HS1_LD 264
__global__ __launch_bounds__(256) void k_gemm1(
    const float* __restrict__ x, const half_t* __restrict__ W1T,
    const float* __restrict__ a_s1, const float* __restrict__ a_d1,
    half_t* __restrict__ h1h, float* __restrict__ l1s, float* __restrict__ l1d) {
    __shared__ half_t xs[32 * XS1_LD];            // 8.7 KB
    __shared__ half_t hs[32 * HS1_LD];            // 16.9 KB
    const int base = blockIdx.x * 32;
    const int rows = min(32, N_NODES - base);
    const int tid = threadIdx.x;
    // stage x tile as fp16
    for (int idx = tid; idx < 32 * 16; idx += 256) {
        int row = idx >> 4, c8 = (idx & 15) * 8;
        half8_t hv = {0, 0, 0, 0, 0, 0, 0, 0};
        if (row < rows) {
            const float4 v0 = *(const float4*)(x + (size_t)(base + row) * IN_CH + c8);
            const float4 v1 = *(const float4*)(x + (size_t)(base + row) * IN_CH + c8 + 4);
            hv[0] = (half_t)v0.x; hv[1] = (half_t)v0.y; hv[2] = (half_t)v0.z; hv[3] = (half_t)v0.w;
            hv[4] = (half_t)v1.x; hv[5] = (half_t)v1.y; hv[6] = (half_t)v1.z; hv[7] = (half_t)v1.w;
        }
        *(half8_t*)(xs + row * XS1_LD + c8) = hv;
    }
    __syncthreads();
    const int lane = tid & 63;
    const int w = tid >> 6;
    const int cw = w * 64;                        // wave's 64-col slice
    const int lr = lane & 15;
    const int lg = lane >> 4;
    f32x4 acc[2][4];
    #pragma unroll
    for (int i = 0; i < 2; ++i)
        #pragma unroll
        for (int j = 0; j < 4; ++j)
            #pragma unroll
            for (int r = 0; r < 4; ++r) acc[i][j][r] = 0.f;

    #pragma unroll
    for (int kt = 0; kt < 4; ++kt) {
        const int k0 = kt * 32 + lg * 8;
        half8_t A0 = *(const half8_t*)(xs + lr * XS1_LD + k0);
        half8_t A1 = *(const half8_t*)(xs + (16 + lr) * XS1_LD + k0);
        #pragma unroll
        for (int ct = 0; ct < 4; ++ct) {
            half8_t B = *(const half8_t*)(W1T + (size_t)(cw + ct * 16 + lr) * IN_CH + k0);
            acc[0][ct] = __builtin_amdgcn_mfma_f32_16x16x32_f16(A0, B, acc[0][ct], 0, 0, 0);
            acc[1][ct] = __builtin_amdgcn_mfma_f32_16x16x32_f16(A1, B, acc[1][ct], 0, 0, 0);
        }
    }
    // C layout: col = lane&15, row = (lane>>4)*4 + r  -> LDS transpose, coalesced store
    #pragma unroll
    for (int rt = 0; rt < 2; ++rt)
        #pragma unroll
        for (int ct = 0; ct < 4; ++ct)
            #pragma unroll
            for (int r = 0; r < 4; ++r)
                hs[(rt * 16 + lg * 4 + r) * HS1_LD + cw + ct * 16 + lr] = (half_t)acc[rt][ct][r];
    __syncthreads();
    for (int idx = tid; idx < 32 * 32; idx += 256) {
        int row = idx >> 5, c8 = (idx & 31) * 8;
        if (row < rows)
            *(float4*)(h1h + (size_t)(base + row) * C1 + c8) = *(const float4*)(hs + row * HS1_LD + c8);
    }
    // fused logits: wave w handles rows w*8..w*8+7; lane covers ch lane*4..+3
    {
        const int c4l = lane * 4;
        const float4 av = *(const float4*)(a_s1 + c4l);
        const float4 dv = *(const float4*)(a_d1 + c4l);
        #pragma unroll
        for (int i = 0; i < 8; ++i) {
            int row = w * 8 + i;
            if (row < rows) {
                float2 rr = *(const float2*)(hs + row * HS1_LD + c4l);
                half2_t ha = __builtin_bit_cast(half2_t, rr.x);
                half2_t hb = __builtin_bit_cast(half2_t, rr.y);
                float ps = (float)ha[0] * av.x + (float)ha[1] * av.y + (float)hb[0] * av.z + (float)hb[1] * av.w;
                float pd = (float)ha[0] * dv.x + (float)ha[1] * dv.y + (float)hb[0] * dv.z + (float)hb[1] * dv.w;
                #pragma unroll
                for (int d = 1; d < 16; d <<= 1) {
                    ps += __shfl_xor(ps, d, 64);
                    pd += __shfl_xor(pd, d, 64);
                }
                if ((lane & 15) == 0) {
                    int hh = lane >> 4;
                    l1s[(base + row) * HEADS + hh] = ps;
                    l1d[(base + row) * HEADS + hh] = pd;
                }
            }
        }
    }
}

// ---------------- agg1: wave per node, fp16 gather, no max pass ----------------
__global__ __launch_bounds__(256) void k_agg1(
    const half_t* __restrict__ h1h, const float* __restrict__ l1s, const float* __restrict__ l1d,
    const int* __restrict__ rowptr, const int* __restrict__ csr_src,
    const float* __restrict__ b1, half_t* __restrict__ out1h) {
    const int tid = threadIdx.x;
    const int lane = tid & 63;
    const int wv = tid >> 6;
    const int n = blockIdx.x * 4 + wv;
    if (n >= N_NODES) return;                     // no syncthreads below
    const int beg = rowptr[n], end = rowptr[n + 1];
    const float4 ldv = *(const float4*)(l1d + (size_t)n * 4);
    const int hh = lane >> 4;
    const float ldh = (hh & 2) ? ((hh & 1) ? ldv.w : ldv.z) : ((hh & 1) ? ldv.y : ldv.x);
    const float* l1sh = l1s + hh;
    const float2* hrows = (const float2*)h1h;     // 64 float2 per row
    float a0 = 0.f, a1 = 0.f, a2 = 0.f, a3 = 0.f, dn = 0.f;
    int e = beg;
    for (; e + 3 < end; e += 4) {
        int s0 = csr_src[e], s1 = csr_src[e + 1], s2 = csr_src[e + 2], s3 = csr_src[e + 3];
        float2 r0 = hrows[(size_t)s0 * 64 + lane];
        float2 r1 = hrows[(size_t)s1 * 64 + lane];
        float2 r2 = hrows[(size_t)s2 * 64 + lane];
        float2 r3 = hrows[(size_t)s3 * 64 + lane];
        float g0 = l1sh[(size_t)s0 * 4] + ldh;
        float g1 = l1sh[(size_t)s1 * 4] + ldh;
        float g2 = l1sh[(size_t)s2 * 4] + ldh;
        float g3 = l1sh[(size_t)s3 * 4] + ldh;
        g0 = (g0 > 0.f) ? g0 : NEG_SLOPE * g0;
        g1 = (g1 > 0.f) ? g1 : NEG_SLOPE * g1;
        g2 = (g2 > 0.f) ? g2 : NEG_SLOPE * g2;
        g3 = (g3 > 0.f) ? g3 : NEG_SLOPE * g3;
        float w0 = __expf(g0), w1 = __expf(g1), w2 = __expf(g2), w3 = __expf(g3);
        dn += (w0 + w1) + (w2 + w3);
        half2_t p;
        p = __builtin_bit_cast(half2_t, r0.x); a0 = fmaf(w0, (float)p[0], a0); a1 = fmaf(w0, (float)p[1], a1);
        p = __builtin_bit_cast(half2_t, r0.y); a2 = fmaf(w0, (float)p[0], a2); a3 = fmaf(w0, (float)p[1], a3);
        p = __builtin_bit_cast(half2_t, r1.x); a0 = fmaf(w1, (float)p[0], a0); a1 = fmaf(w1, (float)p[1], a1);
        p = __builtin_bit_cast(half2_t, r1.y); a2 = fmaf(w1, (float)p[0], a2); a3 = fmaf(w1, (float)p[1], a3);
        p = __builtin_bit_cast(half2_t, r2.x); a0 = fmaf(w2, (float)p[0], a0); a1 = fmaf(w2, (float)p[1], a1);
        p = __builtin_bit_cast(half2_t, r2.y); a2 = fmaf(w2, (float)p[0], a2); a3 = fmaf(w2, (float)p[1], a3);
        p = __builtin_bit_cast(half2_t, r3.x); a0 = fmaf(w3, (float)p[0], a0); a1 = fmaf(w3, (float)p[1], a1);
        p = __builtin_bit_cast(half2_t, r3.y); a2 = fmaf(w3, (float)p[0], a2); a3 = fmaf(w3, (float)p[1], a3);
    }
    for (; e < end; ++e) {
        int s0 = csr_src[e];
        float2 r0 = hrows[(size_t)s0 * 64 + lane];
        float g0 = l1sh[(size_t)s0 * 4] + ldh;
        g0 = (g0 > 0.f) ? g0 : NEG_SLOPE * g0;
        float w0 = __expf(g0);
        dn += w0;
        half2_t p;
        p = __builtin_bit_cast(half2_t, r0.x); a0 = fmaf(w0, (float)p[0], a0); a1 = fmaf(w0, (float)p[1], a1);
        p = __builtin_bit_cast(half2_t, r0.y); a2 = fmaf(w0, (float)p[0], a2); a3 = fmaf(w0, (float)p[1], a3);
    }
    const float inv = 1.f / (dn + EPSV);
    const int c4 = lane * 4;
    const float4 bv = *(const float4*)(b1 + c4);
    half2_t pa, pb;
    pa[0] = (half_t)fmaxf(fmaf(a0, inv, bv.x), 0.f);
    pa[1] = (half_t)fmaxf(fmaf(a1, inv, bv.y), 0.f);
    pb[0] = (half_t)fmaxf(fmaf(a2, inv, bv.z), 0.f);
    pb[1] = (half_t)fmaxf(fmaf(a3, inv, bv.w), 0.f);
    float2 st;
    st.x = __builtin_bit_cast(float, pa);
    st.y = __builtin_bit_cast(float, pb);
    *(float2*)(out1h + (size_t)n * C1 + c4) = st;
}

// ---------------- GEMM2 (MFMA fp16): h2 = out1 @ W2, 32x64 tile, K=256; fused logits ----------------
#define XS2_LD 264
#define HS2_LD 72
__global__ __launch_bounds__(256) void k_gemm2(
    const half_t* __restrict__ out1h, const half_t* __restrict__ W2T,
    const float* __restrict__ a_s2, const float* __restrict__ a_d2,
    half_t* __restrict__ h2h, float* __restrict__ l2s, float* __restrict__ l2d) {
    __shared__ half_t xs[32 * XS2_LD];            // 16.9 KB
    __shared__ half_t hs[32 * HS2_LD];            // 4.6 KB
    const int base = blockIdx.x * 32;
    const int rows = min(32, N_NODES - base);
    const int tid = threadIdx.x;
    for (int idx = tid; idx < 32 * 32; idx += 256) {
        int row = idx >> 5, c8 = (idx & 31) * 8;
        half8_t hv = {0, 0, 0, 0, 0, 0, 0, 0};
        if (row < rows) hv = *(const half8_t*)(out1h + (size_t)(base + row) * C1 + c8);
        *(half8_t*)(xs + row * XS2_LD + c8) = hv;
    }
    __syncthreads();
    const int lane = tid & 63;
    const int w = tid >> 6;                       // wave w -> cols 16w..16w+15
    const int lr = lane & 15;
    const int lg = lane >> 4;
    f32x4 acc0, acc1;
    #pragma unroll
    for (int r = 0; r < 4; ++r) { acc0[r] = 0.f; acc1[r] = 0.f; }
    #pragma unroll
    for (int kt = 0; kt < 8; ++kt) {
        const int k0 = kt * 32 + lg * 8;
        half8_t A0 = *(const half8_t*)(xs + lr * XS2_LD + k0);
        half8_t A1 = *(const half8_t*)(xs + (16 + lr) * XS2_LD + k0);
        half8_t B  = *(const half8_t*)(W2T + (size_t)(w * 16 + lr) * C1 + k0);
        acc0 = __builtin_amdgcn_mfma_f32_16x16x32_f16(A0, B, acc0, 0, 0, 0);
        acc1 = __builtin_amdgcn_mfma_f32_16x16x32_f16(A1, B, acc1, 0, 0, 0);
    }
    #pragma unroll
    for (int r = 0; r < 4; ++r) {
        hs[(lg * 4 + r) * HS2_LD + w * 16 + lr] = (half_t)acc0[r];
        hs[(16 + lg * 4 + r) * HS2_LD + w * 16 + lr] = (half_t)acc1[r];
    }
    __syncthreads();
    {
        int idx = tid;                            // 32 rows x 8 chunks == 256
        int row = idx >> 3, c8 = (idx & 7) * 8;
        if (row < rows)
            *(float4*)(h2h + (size_t)(base + row) * HID + c8) = *(const float4*)(hs + row * HS2_LD + c8);
    }
    // fused logits: wave w handles rows w*8..w*8+7; lane covers one channel
    {
        const float vas = a_s2[lane];
        const float vad = a_d2[lane];
        #pragma unroll
        for (int i = 0; i < 8; ++i) {
            int row = w * 8 + i;
            if (row < rows) {
                float v = (float)hs[row * HS2_LD + lane];
                float ps = v * vas, pd = v * vad;
                #pragma unroll
                for (int d = 1; d < 64; d <<= 1) {
                    ps += __shfl_xor(ps, d, 64);
                    pd += __shfl_xor(pd, d, 64);
                }
                if (lane == 0) { l2s[base + row] = ps; l2d[base + row] = pd; }
            }
        }
    }
}

// ---------------- agg2 + final linear: wave per node, unrolled x4, no max pass ----------------
__global__ __launch_bounds__(256) void k_agg2(
    const half_t* __restrict__ h2h, const float* __restrict__ l2s, const float* __restrict__ l2d,
    const int* __restrict__ rowptr, const int* __restrict__ csr_src,
    const float* __restrict__ b2, const float* __restrict__ Wl, const float* __restrict__ bl,
    float* __restrict__ out) {
    __shared__ float Wls[HID * OUT_CH];           // 16 KB
    __shared__ float vsh[4][HID];
    const int tid = threadIdx.x;
    const int lane = tid & 63;
    const int wv = tid >> 6;
    for (int i = tid; i < HID * OUT_CH; i += 256) Wls[i] = Wl[i];
    const int n = blockIdx.x * 4 + wv;
    const bool active = (n < N_NODES);
    if (active) {
        const int beg = rowptr[n], end = rowptr[n + 1];
        const float ld = l2d[n];
        // half-wave per edge; each lane covers 2 channels; unroll x4 edges per half-wave
        const int eo = lane >> 5;
        const int c2i = lane & 31;                // half2 index within row
        float a0 = 0.f, a1 = 0.f, dn = 0.f;
        int e = beg + eo;
        for (; e + 6 < end; e += 8) {
            int s0 = csr_src[e], s1 = csr_src[e + 2], s2 = csr_src[e + 4], s3 = csr_src[e + 6];
            float g0 = l2s[s0] + ld;
            float g1 = l2s[s1] + ld;
            float g2 = l2s[s2] + ld;
            float g3 = l2s[s3] + ld;
            half2_t v0 = ((const half2_t*)(h2h + (size_t)s0 * HID))[c2i];
            half2_t v1 = ((const half2_t*)(h2h + (size_t)s1 * HID))[c2i];
            half2_t v2 = ((const half2_t*)(h2h + (size_t)s2 * HID))[c2i];
            half2_t v3 = ((const half2_t*)(h2h + (size_t)s3 * HID))[c2i];
            g0 = (g0 > 0.f) ? g0 : NEG_SLOPE * g0;
            g1 = (g1 > 0.f) ? g1 : NEG_SLOPE * g1;
            g2 = (g2 > 0.f) ? g2 : NEG_SLOPE * g2;
            g3 = (g3 > 0.f) ? g3 : NEG_SLOPE * g3;
            float w0 = __expf(g0), w1 = __expf(g1), w2 = __expf(g2), w3 = __expf(g3);
            dn += (w0 + w1) + (w2 + w3);
            a0 = fmaf(w0, (float)v0[0], a0); a1 = fmaf(w0, (float)v0[1], a1);
            a0 = fmaf(w1, (float)v1[0], a0); a1 = fmaf(w1, (float)v1[1], a1);
            a0 = fmaf(w2, (float)v2[0], a0); a1 = fmaf(w2, (float)v2[1], a1);
            a0 = fmaf(w3, (float)v3[0], a0); a1 = fmaf(w3, (float)v3[1], a1);
        }
        for (; e < end; e += 2) {
            int s = csr_src[e];
            float lg = l2s[s] + ld;
            lg = (lg > 0.f) ? lg : NEG_SLOPE * lg;
            float w = __expf(lg);
            dn += w;
            half2_t hv = ((const half2_t*)(h2h + (size_t)s * HID))[c2i];
            a0 = fmaf(w, (float)hv[0], a0);
            a1 = fmaf(w, (float)hv[1], a1);
        }
        a0 += __shfl_xor(a0, 32, 64);
        a1 += __shfl_xor(a1, 32, 64);
        dn += __shfl_xor(dn, 32, 64);
        if (eo == 0) {
            float inv = 1.f / (dn + EPSV);
            int ch2 = c2i * 2;
            vsh[wv][ch2]     = fmaf(a0, inv, b2[ch2]);
            vsh[wv][ch2 + 1] = fmaf(a1, inv, b2[ch2 + 1]);
        }
    }
    __syncthreads();
    if (active) {
        float o = bl[lane];
        #pragma unroll
        for (int c2 = 0; c2 < HID; ++c2)
            o = fmaf(vsh[wv][c2], Wls[c2 * OUT_CH + lane], o);
        out[(size_t)n * OUT_CH + lane] = o;
    }
}

extern "C" void kernel_launch(void* const* d_in, const int* in_sizes, int n_in,
                              void* d_out, int out_size, void* d_ws, size_t ws_size,
                              hipStream_t stream) {
    const float* x   = (const float*)d_in[0];
    const int*   ei  = (const int*)d_in[1];
    const float* W1  = (const float*)d_in[2];
    const float* as1 = (const float*)d_in[3];
    const float* ad1 = (const float*)d_in[4];
    const float* b1  = (const float*)d_in[5];
    const float* W2  = (const float*)d_in[6];
    const float* as2 = (const float*)d_in[7];
    const float* ad2 = (const float*)d_in[8];
    const float* b2  = (const float*)d_in[9];
    const float* Wl  = (const float*)d_in[10];
    const float* bl  = (const float*)d_in[11];
    float* out = (float*)d_out;

    char* p = (char*)d_ws;
    auto alloc = [&](size_t bytes) {
        char* r = p;
        p += (bytes + 255) & ~(size_t)255;
        return r;
    };
    int* deg      = (int*)alloc((size_t)N_NODES * 4);
    int* rowptr   = (int*)alloc((size_t)(N_NODES + 1) * 4);
    int* cursor   = (int*)alloc((size_t)N_NODES * 4);
    int* csr_src  = (int*)alloc((size_t)E_TOT * 4);
    int* bsum     = (int*)alloc(64 * 4);
    int* boff     = (int*)alloc(64 * 4);
    half_t* W1T   = (half_t*)alloc((size_t)IN_CH * C1 * 2);
    half_t* W2T   = (half_t*)alloc((size_t)C1 * HID * 2);
    half_t* h1h   = (half_t*)alloc((size_t)N_NODES * C1 * 2);
    float* l1s    = (float*)alloc((size_t)N_NODES * HEADS * 4);
    float* l1d    = (float*)alloc((size_t)N_NODES * HEADS * 4);
    half_t* out1h = (half_t*)alloc((size_t)N_NODES * C1 * 2);
    half_t* h2h   = (half_t*)alloc((size_t)N_NODES * HID * 2);
    float* l2s    = (float*)alloc((size_t)N_NODES * 4);
    float* l2d    = (float*)alloc((size_t)N_NODES * 4);

    (void)hipMemsetAsync(deg, 0, (size_t)N_NODES * 4, stream);
    k_prep<<<(IN_CH * C1 + C1 * HID + 255) / 256, 256, 0, stream>>>(W1, W2, W1T, W2T);
    k_count<<<(E_TOT + 255) / 256, 256, 0, stream>>>(ei, deg);
    k_bsum<<<NB_SCAN, 256, 0, stream>>>(deg, bsum);
    k_bscan<<<1, 64, 0, stream>>>(bsum, boff, rowptr);
    k_scanf<<<NB_SCAN, 1024, 0, stream>>>(deg, boff, rowptr, cursor);
    k_scatter<<<(E_TOT + 255) / 256, 256, 0, stream>>>(ei, cursor, csr_src);
    k_gemm1<<<(N_NODES + 31) / 32, 256, 0, stream>>>(x, W1T, as1, ad1, h1h, l1s, l1d);
    k_agg1<<<(N_NODES + 3) / 4, 256, 0, stream>>>(h1h, l1s, l1d, rowptr, csr_src, b1, out1h);
    k_gemm2<<<(N_NODES + 31) / 32, 256, 0, stream>>>(out1h, W2T, as2, ad2, h2h, l2s, l2d);
    k_agg2<<<(N_NODES + 3) / 4, 256, 0, stream>>>(h2h, l2s, l2d, rowptr, csr_src, b2, Wl, bl, out);
}

// Round 6
// 264.946 us; speedup vs baseline: 2.3193x; 1.0104x over previous
//
#include <hip/hip_runtime.h>

#define N_NODES 50000
#define N_EDGES 800000
#define E_TOT   850000            // N_EDGES + N_NODES self loops
#define IN_CH   128
#define HID     64
#define HEADS   4
#define C1      256               // HEADS*HID
#define OUT_CH  64
#define NEG_SLOPE 0.2f
#define EPSV    1e-16f

typedef _Float16 half_t;
typedef _Float16 half2_t __attribute__((ext_vector_type(2)));
typedef _Float16 half8_t __attribute__((ext_vector_type(8)));
typedef float f32x4 __attribute__((ext_vector_type(4)));

__device__ __forceinline__ float lrelu(float v) {
    return (v > 0.f) ? v : NEG_SLOPE * v;
}

__device__ __forceinline__ void acc8(float (&a)[8], float w, float4 r) {
    half2_t p;
    p = __builtin_bit_cast(half2_t, r.x); a[0] = fmaf(w, (float)p[0], a[0]); a[1] = fmaf(w, (float)p[1], a[1]);
    p = __builtin_bit_cast(half2_t, r.y); a[2] = fmaf(w, (float)p[0], a[2]); a[3] = fmaf(w, (float)p[1], a[3]);
    p = __builtin_bit_cast(half2_t, r.z); a[4] = fmaf(w, (float)p[0], a[4]); a[5] = fmaf(w, (float)p[1], a[5]);
    p = __builtin_bit_cast(half2_t, r.w); a[6] = fmaf(w, (float)p[0], a[6]); a[7] = fmaf(w, (float)p[1], a[7]);
}

// ---------------- weight prep: W1 -> W1T fp16 [256][128], W2 -> W2T fp16 [64][256] ----------------
__global__ __launch_bounds__(256) void k_prep(const float* __restrict__ W1,
                                              const float* __restrict__ W2,
                                              half_t* __restrict__ W1T,
                                              half_t* __restrict__ W2T) {
    int i = blockIdx.x * 256 + threadIdx.x;
    if (i < IN_CH * C1) {
        int c = i >> 7, k = i & 127;
        W1T[i] = (half_t)W1[k * C1 + c];
    }
    int j = i - IN_CH * C1;
    if (j >= 0 && j < C1 * HID) {
        int c = j >> 8, k = j & 255;
        W2T[j] = (half_t)W2[k * HID + c];
    }
}

// ---------------- CSR build (group edges by dst) ----------------
__global__ void k_count(const int* __restrict__ ei, int* __restrict__ deg) {
    int e = blockIdx.x * blockDim.x + threadIdx.x;
    if (e >= E_TOT) return;
    int d = (e < N_EDGES) ? ei[N_EDGES + e] : (e - N_EDGES);
    atomicAdd(&deg[d], 1);
}

#define SCAN_CH 1024
#define NB_SCAN ((N_NODES + SCAN_CH - 1) / SCAN_CH)   // 49

__global__ __launch_bounds__(256) void k_bsum(const int* __restrict__ deg,
                                              int* __restrict__ bsum) {
    const int b = blockIdx.x;
    const int tid = threadIdx.x;
    int sum = 0;
    for (int i = tid; i < SCAN_CH; i += 256) {
        int idx = b * SCAN_CH + i;
        sum += (idx < N_NODES) ? deg[idx] : 0;
    }
    #pragma unroll
    for (int d = 1; d < 64; d <<= 1) sum += __shfl_xor(sum, d, 64);
    __shared__ int ws[4];
    if ((tid & 63) == 0) ws[tid >> 6] = sum;
    __syncthreads();
    if (tid == 0) bsum[b] = ws[0] + ws[1] + ws[2] + ws[3];
}

__global__ void k_bscan(const int* __restrict__ bsum, int* __restrict__ boff,
                        int* __restrict__ rowptr) {
    int tid = threadIdx.x;                        // 64 threads, 1 block
    int v = (tid < NB_SCAN) ? bsum[tid] : 0;
    int s = v;
    #pragma unroll
    for (int d = 1; d < 64; d <<= 1) {
        int t = __shfl_up(s, d, 64);
        if (tid >= d) s += t;
    }
    boff[tid] = s - v;
    if (tid == 0) rowptr[N_NODES] = E_TOT;
}

__global__ __launch_bounds__(1024) void k_scanf(const int* __restrict__ deg,
                                                const int* __restrict__ boff,
                                                int* __restrict__ rowptr,
                                                int* __restrict__ cursor) {
    const int b = blockIdx.x;
    const int tid = threadIdx.x;
    const int lane = tid & 63;
    const int wv = tid >> 6;                      // 16 waves
    const int i = b * SCAN_CH + tid;
    int v = (i < N_NODES) ? deg[i] : 0;
    int s = v;
    #pragma unroll
    for (int d = 1; d < 64; d <<= 1) {
        int t = __shfl_up(s, d, 64);
        if (lane >= d) s += t;
    }
    __shared__ int wsum[16];
    if (lane == 63) wsum[wv] = s;
    __syncthreads();
    if (wv == 0 && lane < 16) {
        int w = wsum[lane];
        #pragma unroll
        for (int d = 1; d < 16; d <<= 1) {
            int t = __shfl_up(w, d, 64);
            if (lane >= d) w += t;
        }
        wsum[lane] = w;
    }
    __syncthreads();
    int excl = boff[b] + ((wv > 0) ? wsum[wv - 1] : 0) + (s - v);
    if (i < N_NODES) { rowptr[i] = excl; cursor[i] = excl; }
}

__global__ void k_scatter(const int* __restrict__ ei, int* __restrict__ cursor,
                          int* __restrict__ csr_src) {
    int e = blockIdx.x * blockDim.x + threadIdx.x;
    if (e >= E_TOT) return;
    int s, d;
    if (e < N_EDGES) { s = ei[e]; d = ei[N_EDGES + e]; }
    else             { s = d = e - N_EDGES; }
    int pos = atomicAdd(&cursor[d], 1);
    csr_src[pos] = s;
}

// ---------------- GEMM1 (MFMA fp16): h1 = x @ W1, 32x256 tile, K=128; fused logits ----------------
#define XS1_LD 136
#define HS1_LD 264
__global__ __launch_bounds__(256) void k_gemm1(
    const float* __restrict__ x, const half_t* __restrict__ W1T,
    const float* __restrict__ a_s1, const float* __restrict__ a_d1,
    half_t* __restrict__ h1h, float* __restrict__ l1s, float* __restrict__ l1d) {
    __shared__ half_t xs[32 * XS1_LD];            // 8.7 KB
    __shared__ half_t hs[32 * HS1_LD];            // 16.9 KB
    const int base = blockIdx.x * 32;
    const int rows = min(32, N_NODES - base);
    const int tid = threadIdx.x;
    // stage x tile as fp16
    for (int idx = tid; idx < 32 * 16; idx += 256) {
        int row = idx >> 4, c8 = (idx & 15) * 8;
        half8_t hv = {0, 0, 0, 0, 0, 0, 0, 0};
        if (row < rows) {
            const float4 v0 = *(const float4*)(x + (size_t)(base + row) * IN_CH + c8);
            const float4 v1 = *(const float4*)(x + (size_t)(base + row) * IN_CH + c8 + 4);
            hv[0] = (half_t)v0.x; hv[1] = (half_t)v0.y; hv[2] = (half_t)v0.z; hv[3] = (half_t)v0.w;
            hv[4] = (half_t)v1.x; hv[5] = (half_t)v1.y; hv[6] = (half_t)v1.z; hv[7] = (half_t)v1.w;
        }
        *(half8_t*)(xs + row * XS1_LD + c8) = hv;
    }
    __syncthreads();
    const int lane = tid & 63;
    const int w = tid >> 6;
    const int cw = w * 64;                        // wave's 64-col slice
    const int lr = lane & 15;
    const int lg = lane >> 4;
    f32x4 acc[2][4];
    #pragma unroll
    for (int i = 0; i < 2; ++i)
        #pragma unroll
        for (int j = 0; j < 4; ++j)
            #pragma unroll
            for (int r = 0; r < 4; ++r) acc[i][j][r] = 0.f;

    #pragma unroll
    for (int kt = 0; kt < 4; ++kt) {
        const int k0 = kt * 32 + lg * 8;
        half8_t A0 = *(const half8_t*)(xs + lr * XS1_LD + k0);
        half8_t A1 = *(const half8_t*)(xs + (16 + lr) * XS1_LD + k0);
        #pragma unroll
        for (int ct = 0; ct < 4; ++ct) {
            half8_t B = *(const half8_t*)(W1T + (size_t)(cw + ct * 16 + lr) * IN_CH + k0);
            acc[0][ct] = __builtin_amdgcn_mfma_f32_16x16x32_f16(A0, B, acc[0][ct], 0, 0, 0);
            acc[1][ct] = __builtin_amdgcn_mfma_f32_16x16x32_f16(A1, B, acc[1][ct], 0, 0, 0);
        }
    }
    // C layout: col = lane&15, row = (lane>>4)*4 + r  -> LDS transpose, coalesced store
    #pragma unroll
    for (int rt = 0; rt < 2; ++rt)
        #pragma unroll
        for (int ct = 0; ct < 4; ++ct)
            #pragma unroll
            for (int r = 0; r < 4; ++r)
                hs[(rt * 16 + lg * 4 + r) * HS1_LD + cw + ct * 16 + lr] = (half_t)acc[rt][ct][r];
    __syncthreads();
    for (int idx = tid; idx < 32 * 32; idx += 256) {
        int row = idx >> 5, c8 = (idx & 31) * 8;
        if (row < rows)
            *(float4*)(h1h + (size_t)(base + row) * C1 + c8) = *(const float4*)(hs + row * HS1_LD + c8);
    }
    // fused logits: wave w handles rows w*8..w*8+7; lane covers ch lane*4..+3
    {
        const int c4l = lane * 4;
        const float4 av = *(const float4*)(a_s1 + c4l);
        const float4 dv = *(const float4*)(a_d1 + c4l);
        #pragma unroll
        for (int i = 0; i < 8; ++i) {
            int row = w * 8 + i;
            if (row < rows) {
                float2 rr = *(const float2*)(hs + row * HS1_LD + c4l);
                half2_t ha = __builtin_bit_cast(half2_t, rr.x);
                half2_t hb = __builtin_bit_cast(half2_t, rr.y);
                float ps = (float)ha[0] * av.x + (float)ha[1] * av.y + (float)hb[0] * av.z + (float)hb[1] * av.w;
                float pd = (float)ha[0] * dv.x + (float)ha[1] * dv.y + (float)hb[0] * dv.z + (float)hb[1] * dv.w;
                #pragma unroll
                for (int d = 1; d < 16; d <<= 1) {
                    ps += __shfl_xor(ps, d, 64);
                    pd += __shfl_xor(pd, d, 64);
                }
                if ((lane & 15) == 0) {
                    int hh = lane >> 4;
                    l1s[(base + row) * HEADS + hh] = ps;
                    l1d[(base + row) * HEADS + hh] = pd;
                }
            }
        }
    }
}

// ---------------- agg1: half-wave per edge, 8 fp16 ch/lane (16B loads), no max pass ----------------
__global__ __launch_bounds__(256) void k_agg1(
    const half_t* __restrict__ h1h, const float* __restrict__ l1s, const float* __restrict__ l1d,
    const int* __restrict__ rowptr, const int* __restrict__ csr_src,
    const float* __restrict__ b1, half_t* __restrict__ out1h) {
    const int tid = threadIdx.x;
    const int lane = tid & 63;
    const int wv = tid >> 6;
    const int n = blockIdx.x * 4 + wv;
    if (n >= N_NODES) return;                     // no syncthreads below
    const int beg = rowptr[n], end = rowptr[n + 1];
    const float4 ldv = *(const float4*)(l1d + (size_t)n * 4);
    const int half = lane >> 5;                   // edge stream 0/1
    const int l32 = lane & 31;
    const int c8 = l32 * 8;                       // this lane's 8 channels
    const int hh = l32 >> 3;                      // head of those channels
    const float ldh = (hh & 2) ? ((hh & 1) ? ldv.w : ldv.z) : ((hh & 1) ? ldv.y : ldv.x);
    const float* l1sh = l1s + hh;
    const float4* hrows = (const float4*)h1h;     // 32 float4 per row
    float a[8] = {0.f, 0.f, 0.f, 0.f, 0.f, 0.f, 0.f, 0.f};
    float dn = 0.f;
    int e = beg + half;
    for (; e + 6 < end; e += 8) {                 // 4 edges per half-wave in flight
        int s0 = csr_src[e], s1 = csr_src[e + 2], s2 = csr_src[e + 4], s3 = csr_src[e + 6];
        float4 r0 = hrows[s0 * 32 + l32];
        float4 r1 = hrows[s1 * 32 + l32];
        float4 r2 = hrows[s2 * 32 + l32];
        float4 r3 = hrows[s3 * 32 + l32];
        float g0 = l1sh[s0 * 4] + ldh;
        float g1 = l1sh[s1 * 4] + ldh;
        float g2 = l1sh[s2 * 4] + ldh;
        float g3 = l1sh[s3 * 4] + ldh;
        float w0 = __expf(lrelu(g0));
        float w1 = __expf(lrelu(g1));
        float w2 = __expf(lrelu(g2));
        float w3 = __expf(lrelu(g3));
        dn += (w0 + w1) + (w2 + w3);
        acc8(a, w0, r0);
        acc8(a, w1, r1);
        acc8(a, w2, r2);
        acc8(a, w3, r3);
    }
    for (; e < end; e += 2) {
        int s0 = csr_src[e];
        float4 r0 = hrows[s0 * 32 + l32];
        float g0 = l1sh[s0 * 4] + ldh;
        float w0 = __expf(lrelu(g0));
        dn += w0;
        acc8(a, w0, r0);
    }
    // combine the two half-wave edge streams
    #pragma unroll
    for (int j = 0; j < 8; ++j) a[j] += __shfl_xor(a[j], 32, 64);
    dn += __shfl_xor(dn, 32, 64);
    if (half == 0) {
        const float inv = 1.f / (dn + EPSV);
        const float4 bv0 = *(const float4*)(b1 + c8);
        const float4 bv1 = *(const float4*)(b1 + c8 + 4);
        half2_t p01, p23, p45, p67;
        p01[0] = (half_t)fmaxf(fmaf(a[0], inv, bv0.x), 0.f);
        p01[1] = (half_t)fmaxf(fmaf(a[1], inv, bv0.y), 0.f);
        p23[0] = (half_t)fmaxf(fmaf(a[2], inv, bv0.z), 0.f);
        p23[1] = (half_t)fmaxf(fmaf(a[3], inv, bv0.w), 0.f);
        p45[0] = (half_t)fmaxf(fmaf(a[4], inv, bv1.x), 0.f);
        p45[1] = (half_t)fmaxf(fmaf(a[5], inv, bv1.y), 0.f);
        p67[0] = (half_t)fmaxf(fmaf(a[6], inv, bv1.z), 0.f);
        p67[1] = (half_t)fmaxf(fmaf(a[7], inv, bv1.w), 0.f);
        float4 st;
        st.x = __builtin_bit_cast(float, p01);
        st.y = __builtin_bit_cast(float, p23);
        st.z = __builtin_bit_cast(float, p45);
        st.w = __builtin_bit_cast(float, p67);
        *(float4*)(out1h + (size_t)n * C1 + c8) = st;
    }
}

// ---------------- GEMM2 (MFMA fp16): h2 = out1 @ W2, 32x64 tile, K=256; fused logits ----------------
#define XS2_LD 264
#define HS2_LD 72
__global__ __launch_bounds__(256) void k_gemm2(
    const half_t* __restrict__ out1h, const half_t* __restrict__ W2T,
    const float* __restrict__ a_s2, const float* __restrict__ a_d2,
    half_t* __restrict__ h2h, float* __restrict__ l2s, float* __restrict__ l2d) {
    __shared__ half_t xs[32 * XS2_LD];            // 16.9 KB
    __shared__ half_t hs[32 * HS2_LD];            // 4.6 KB
    const int base = blockIdx.x * 32;
    const int rows = min(32, N_NODES - base);
    const int tid = threadIdx.x;
    for (int idx = tid; idx < 32 * 32; idx += 256) {
        int row = idx >> 5, c8 = (idx & 31) * 8;
        half8_t hv = {0, 0, 0, 0, 0, 0, 0, 0};
        if (row < rows) hv = *(const half8_t*)(out1h + (size_t)(base + row) * C1 + c8);
        *(half8_t*)(xs + row * XS2_LD + c8) = hv;
    }
    __syncthreads();
    const int lane = tid & 63;
    const int w = tid >> 6;                       // wave w -> cols 16w..16w+15
    const int lr = lane & 15;
    const int lg = lane >> 4;
    f32x4 acc0, acc1;
    #pragma unroll
    for (int r = 0; r < 4; ++r) { acc0[r] = 0.f; acc1[r] = 0.f; }
    #pragma unroll
    for (int kt = 0; kt < 8; ++kt) {
        const int k0 = kt * 32 + lg * 8;
        half8_t A0 = *(const half8_t*)(xs + lr * XS2_LD + k0);
        half8_t A1 = *(const half8_t*)(xs + (16 + lr) * XS2_LD + k0);
        half8_t B  = *(const half8_t*)(W2T + (size_t)(w * 16 + lr) * C1 + k0);
        acc0 = __builtin_amdgcn_mfma_f32_16x16x32_f16(A0, B, acc0, 0, 0, 0);
        acc1 = __builtin_amdgcn_mfma_f32_16x16x32_f16(A1, B, acc1, 0, 0, 0);
    }
    #pragma unroll
    for (int r = 0; r < 4; ++r) {
        hs[(lg * 4 + r) * HS2_LD + w * 16 + lr] = (half_t)acc0[r];
        hs[(16 + lg * 4 + r) * HS2_LD + w * 16 + lr] = (half_t)acc1[r];
    }
    __syncthreads();
    {
        int idx = tid;                            // 32 rows x 8 chunks == 256
        int row = idx >> 3, c8 = (idx & 7) * 8;
        if (row < rows)
            *(float4*)(h2h + (size_t)(base + row) * HID + c8) = *(const float4*)(hs + row * HS2_LD + c8);
    }
    // fused logits: wave w handles rows w*8..w*8+7; lane covers one channel
    {
        const float vas = a_s2[lane];
        const float vad = a_d2[lane];
        #pragma unroll
        for (int i = 0; i < 8; ++i) {
            int row = w * 8 + i;
            if (row < rows) {
                float v = (float)hs[row * HS2_LD + lane];
                float ps = v * vas, pd = v * vad;
                #pragma unroll
                for (int d = 1; d < 64; d <<= 1) {
                    ps += __shfl_xor(ps, d, 64);
                    pd += __shfl_xor(pd, d, 64);
                }
                if (lane == 0) { l2s[base + row] = ps; l2d[base + row] = pd; }
            }
        }
    }
}

// ---------------- agg2 + final linear: quarter-wave per edge, no max pass ----------------
__global__ __launch_bounds__(256) void k_agg2(
    const half_t* __restrict__ h2h, const float* __restrict__ l2s, const float* __restrict__ l2d,
    const int* __restrict__ rowptr, const int* __restrict__ csr_src,
    const float* __restrict__ b2, const float* __restrict__ Wl, const float* __restrict__ bl,
    float* __restrict__ out) {
    __shared__ float Wls[HID * OUT_CH];           // 16 KB
    __shared__ float vsh[4][HID];
    const int tid = threadIdx.x;
    const int lane = tid & 63;
    const int wv = tid >> 6;
    for (int i = tid; i < HID * OUT_CH; i += 256) Wls[i] = Wl[i];
    const int n = blockIdx.x * 4 + wv;
    const bool active = (n < N_NODES);
    if (active) {
        const int beg = rowptr[n], end = rowptr[n + 1];
        const float ld = l2d[n];
        const int q = lane >> 4;                  // edge stream 0..3
        const int l16 = lane & 15;                // float2 index within row
        const float2* h2rows = (const float2*)h2h;  // 16 float2 per row
        float a0 = 0.f, a1 = 0.f, a2 = 0.f, a3 = 0.f, dn = 0.f;
        int e = beg + q;
        for (; e + 12 < end; e += 16) {           // 4 edges per quarter-wave in flight
            int s0 = csr_src[e], s1 = csr_src[e + 4], s2 = csr_src[e + 8], s3 = csr_src[e + 12];
            float2 v0 = h2rows[s0 * 16 + l16];
            float2 v1 = h2rows[s1 * 16 + l16];
            float2 v2 = h2rows[s2 * 16 + l16];
            float2 v3 = h2rows[s3 * 16 + l16];
            float g0 = l2s[s0] + ld;
            float g1 = l2s[s1] + ld;
            float g2 = l2s[s2] + ld;
            float g3 = l2s[s3] + ld;
            float w0 = __expf(lrelu(g0));
            float w1 = __expf(lrelu(g1));
            float w2 = __expf(lrelu(g2));
            float w3 = __expf(lrelu(g3));
            dn += (w0 + w1) + (w2 + w3);
            half2_t p;
            p = __builtin_bit_cast(half2_t, v0.x); a0 = fmaf(w0, (float)p[0], a0); a1 = fmaf(w0, (float)p[1], a1);
            p = __builtin_bit_cast(half2_t, v0.y); a2 = fmaf(w0, (float)p[0], a2); a3 = fmaf(w0, (float)p[1], a3);
            p = __builtin_bit_cast(half2_t, v1.x); a0 = fmaf(w1, (float)p[0], a0); a1 = fmaf(w1, (float)p[1], a1);
            p = __builtin_bit_cast(half2_t, v1.y); a2 = fmaf(w1, (float)p[0], a2); a3 = fmaf(w1, (float)p[1], a3);
            p = __builtin_bit_cast(half2_t, v2.x); a0 = fmaf(w2, (float)p[0], a0); a1 = fmaf(w2, (float)p[1], a1);
            p = __builtin_bit_cast(half2_t, v2.y); a2 = fmaf(w2, (float)p[0], a2); a3 = fmaf(w2, (float)p[1], a3);
            p = __builtin_bit_cast(half2_t, v3.x); a0 = fmaf(w3, (float)p[0], a0); a1 = fmaf(w3, (float)p[1], a1);
            p = __builtin_bit_cast(half2_t, v3.y); a2 = fmaf(w3, (float)p[0], a2); a3 = fmaf(w3, (float)p[1], a3);
        }
        for (; e < end; e += 4) {
            int s = csr_src[e];
            float2 v = h2rows[s * 16 + l16];
            float lg = l2s[s] + ld;
            float w = __expf(lrelu(lg));
            dn += w;
            half2_t p;
            p = __builtin_bit_cast(half2_t, v.x); a0 = fmaf(w, (float)p[0], a0); a1 = fmaf(w, (float)p[1], a1);
            p = __builtin_bit_cast(half2_t, v.y); a2 = fmaf(w, (float)p[0], a2); a3 = fmaf(w, (float)p[1], a3);
        }
        // combine the four quarter-wave edge streams
        a0 += __shfl_xor(a0, 16, 64); a0 += __shfl_xor(a0, 32, 64);
        a1 += __shfl_xor(a1, 16, 64); a1 += __shfl_xor(a1, 32, 64);
        a2 += __shfl_xor(a2, 16, 64); a2 += __shfl_xor(a2, 32, 64);
        a3 += __shfl_xor(a3, 16, 64); a3 += __shfl_xor(a3, 32, 64);
        dn += __shfl_xor(dn, 16, 64); dn += __shfl_xor(dn, 32, 64);
        if (q == 0) {
            const float inv = 1.f / (dn + EPSV);
            const float4 bv = *(const float4*)(b2 + l16 * 4);
            float4 vv;
            vv.x = fmaf(a0, inv, bv.x);
            vv.y = fmaf(a1, inv, bv.y);
            vv.z = fmaf(a2, inv, bv.z);
            vv.w = fmaf(a3, inv, bv.w);
            *(float4*)(&vsh[wv][l16 * 4]) = vv;
        }
    }
    __syncthreads();
    if (active) {
        float o = bl[lane];
        #pragma unroll
        for (int c2 = 0; c2 < HID; ++c2)
            o = fmaf(vsh[wv][c2], Wls[c2 * OUT_CH + lane], o);
        out[(size_t)n * OUT_CH + lane] = o;
    }
}

extern "C" void kernel_launch(void* const* d_in, const int* in_sizes, int n_in,
                              void* d_out, int out_size, void* d_ws, size_t ws_size,
                              hipStream_t stream) {
    const float* x   = (const float*)d_in[0];
    const int*   ei  = (const int*)d_in[1];
    const float* W1  = (const float*)d_in[2];
    const float* as1 = (const float*)d_in[3];
    const float* ad1 = (const float*)d_in[4];
    const float* b1  = (const float*)d_in[5];
    const float* W2  = (const float*)d_in[6];
    const float* as2 = (const float*)d_in[7];
    const float* ad2 = (const float*)d_in[8];
    const float* b2  = (const float*)d_in[9];
    const float* Wl  = (const float*)d_in[10];
    const float* bl  = (const float*)d_in[11];
    float* out = (float*)d_out;

    char* p = (char*)d_ws;
    auto alloc = [&](size_t bytes) {
        char* r = p;
        p += (bytes + 255) & ~(size_t)255;
        return r;
    };
    int* deg      = (int*)alloc((size_t)N_NODES * 4);
    int* rowptr   = (int*)alloc((size_t)(N_NODES + 1) * 4);
    int* cursor   = (int*)alloc((size_t)N_NODES * 4);
    int* csr_src  = (int*)alloc((size_t)E_TOT * 4);
    int* bsum     = (int*)alloc(64 * 4);
    int* boff     = (int*)alloc(64 * 4);
    half_t* W1T   = (half_t*)alloc((size_t)IN_CH * C1 * 2);
    half_t* W2T   = (half_t*)alloc((size_t)C1 * HID * 2);
    half_t* h1h   = (half_t*)alloc((size_t)N_NODES * C1 * 2);
    float* l1s    = (float*)alloc((size_t)N_NODES * HEADS * 4);
    float* l1d    = (float*)alloc((size_t)N_NODES * HEADS * 4);
    half_t* out1h = (half_t*)alloc((size_t)N_NODES * C1 * 2);
    half_t* h2h   = (half_t*)alloc((size_t)N_NODES * HID * 2);
    float* l2s    = (float*)alloc((size_t)N_NODES * 4);
    float* l2d    = (float*)alloc((size_t)N_NODES * 4);

    (void)hipMemsetAsync(deg, 0, (size_t)N_NODES * 4, stream);
    k_prep<<<(IN_CH * C1 + C1 * HID + 255) / 256, 256, 0, stream>>>(W1, W2, W1T, W2T);
    k_count<<<(E_TOT + 255) / 256, 256, 0, stream>>>(ei, deg);
    k_bsum<<<NB_SCAN, 256, 0, stream>>>(deg, bsum);
    k_bscan<<<1, 64, 0, stream>>>(bsum, boff, rowptr);
    k_scanf<<<NB_SCAN, 1024, 0, stream>>>(deg, boff, rowptr, cursor);
    k_scatter<<<(E_TOT + 255) / 256, 256, 0, stream>>>(ei, cursor, csr_src);
    k_gemm1<<<(N_NODES + 31) / 32, 256, 0, stream>>>(x, W1T, as1, ad1, h1h, l1s, l1d);
    k_agg1<<<(N_NODES + 3) / 4, 256, 0, stream>>>(h1h, l1s, l1d, rowptr, csr_src, b1, out1h);
    k_gemm2<<<(N_NODES + 31) / 32, 256, 0, stream>>>(out1h, W2T, as2, ad2, h2h, l2s, l2d);
    k_agg2<<<(N_NODES + 3) / 4, 256, 0, stream>>>(h2h, l2s, l2d, rowptr, csr_src, b2, Wl, bl, out);
}